// Round 1
// baseline (6953.526 us; speedup 1.0000x reference)
//
#include <hip/hip_runtime.h>
#include <hip/hip_bf16.h>

// ---------------------------------------------------------------------------
// graphNN: edge-MLP + scatter-sum + 2x TAGConv(k=2) + mean-readout
// Round 1: correct fp32 implementation.
//   - edge GEMM: tiled LDS fp32 GEMM, fused relu + atomic scatter
//   - tagconv rewritten: concat([x,Ax,A2x])@W == x@Wa + prop(x@Wb) + prop2(x@Wc)
//     so props run on 128 dims and no concat is materialized
//   - props via CSR (built once per call): gather-sum, no fp atomics
// ---------------------------------------------------------------------------

// ---------- degree histogram ----------
__global__ void k_deg(const int* __restrict__ dst, int* __restrict__ deg, int E) {
  int i = blockIdx.x * blockDim.x + threadIdx.x;
  int stride = gridDim.x * blockDim.x;
  for (; i < E; i += stride) atomicAdd(&deg[dst[i]], 1);
}

// ---------- exclusive scan over deg -> offsets, cursor; also norm ----------
__global__ void k_scan(const int* __restrict__ deg, float* __restrict__ norm,
                       int* __restrict__ offs, int* __restrict__ cursor, int N) {
  __shared__ int part[1024];
  const int t = threadIdx.x;
  const int C = (N + 1023) >> 10;
  const int b = t * C, e = min(b + C, N);
  int s = 0;
  for (int i = b; i < e; ++i) s += deg[i];
  part[t] = s;
  __syncthreads();
  for (int ofs = 1; ofs < 1024; ofs <<= 1) {
    int v = (t >= ofs) ? part[t - ofs] : 0;
    __syncthreads();
    part[t] += v;
    __syncthreads();
  }
  int base = (t == 0) ? 0 : part[t - 1];
  for (int i = b; i < e; ++i) {
    offs[i] = base;
    cursor[i] = base;
    int d = deg[i];
    base += d;
    norm[i] = rsqrtf((float)max(d, 1));
  }
  if (t == 0) offs[N] = part[1023];
}

// ---------- CSR fill (store src directly; order nondeterministic, fp-benign) --
__global__ void k_csr(const int* __restrict__ src, const int* __restrict__ dst,
                      int* __restrict__ cursor, int* __restrict__ csr_src, int E) {
  int i = blockIdx.x * blockDim.x + threadIdx.x;
  int stride = gridDim.x * blockDim.x;
  for (; i < E; i += stride) {
    int pos = atomicAdd(&cursor[dst[i]], 1);
    csr_src[pos] = src[i];
  }
}

// ---------- edge message GEMM: relu([nf[src],ef] @ W + b), atomic scatter ----
// block tile: 64 edges x 128 cols, K=192 in 3 chunks of 64. micro 4e x 8c.
__global__ __launch_bounds__(256) void k_edge_msg(
    const float* __restrict__ node_fea, const float* __restrict__ edge_fea,
    const int* __restrict__ src, const int* __restrict__ dst,
    const float* __restrict__ W, const float* __restrict__ bias,
    float* __restrict__ h_neigh) {
  __shared__ float sW[64][132];  // [k][col], pad 4
  __shared__ float sX[64][68];   // [k][edge] transposed, pad 4
  const int t = threadIdx.x;
  const int e0 = blockIdx.x * 64;
  const int le = t & 63;   // staging: edge
  const int kg = t >> 6;   // staging: k quarter
  const int eg = t & 15;   // compute: edge group (4 edges)
  const int cg = t >> 4;   // compute: col group (8 cols)
  const int srow = src[e0 + le];

  float acc[4][8];
#pragma unroll
  for (int i = 0; i < 4; ++i)
#pragma unroll
    for (int j = 0; j < 8; ++j) acc[i][j] = 0.f;

  for (int kc = 0; kc < 3; ++kc) {
    __syncthreads();
    // stage W chunk [64][128]
#pragma unroll
    for (int i = 0; i < 8; ++i) {
      int idx = (i * 256 + t) * 4;
      int kk = idx >> 7, cc = idx & 127;
      float4 w4 = *(const float4*)(W + (size_t)(kc * 64 + kk) * 128 + cc);
      *(float4*)&sW[kk][cc] = w4;
    }
    // stage X chunk (transposed): k in [kc*64, kc*64+64)
#pragma unroll
    for (int i = 0; i < 4; ++i) {
      int kk = kg * 16 + i * 4;
      int kglob = kc * 64 + kk;
      float4 v;
      if (kglob < 128)
        v = *(const float4*)(node_fea + (size_t)srow * 128 + kglob);
      else
        v = *(const float4*)(edge_fea + (size_t)(e0 + le) * 64 + (kglob - 128));
      sX[kk + 0][le] = v.x;
      sX[kk + 1][le] = v.y;
      sX[kk + 2][le] = v.z;
      sX[kk + 3][le] = v.w;
    }
    __syncthreads();
#pragma unroll 4
    for (int kk = 0; kk < 64; ++kk) {
      float4 xv = *(const float4*)&sX[kk][eg * 4];
      float4 wa = *(const float4*)&sW[kk][cg * 8];
      float4 wb = *(const float4*)&sW[kk][cg * 8 + 4];
      float xs[4] = {xv.x, xv.y, xv.z, xv.w};
      float ws[8] = {wa.x, wa.y, wa.z, wa.w, wb.x, wb.y, wb.z, wb.w};
#pragma unroll
      for (int i = 0; i < 4; ++i)
#pragma unroll
        for (int j = 0; j < 8; ++j) acc[i][j] = fmaf(xs[i], ws[j], acc[i][j]);
    }
  }
  // epilogue: relu(acc + b) scattered to h_neigh[dst]
  int drow[4];
#pragma unroll
  for (int i = 0; i < 4; ++i) drow[i] = dst[e0 + eg * 4 + i];
#pragma unroll
  for (int j = 0; j < 8; ++j) {
    const int c = cg * 8 + j;
    const float bj = bias[c];
#pragma unroll
    for (int i = 0; i < 4; ++i) {
      float v = acc[i][j] + bj;
      v = v > 0.f ? v : 0.f;
      unsafeAtomicAdd(&h_neigh[(size_t)drow[i] * 128 + c], v);
    }
  }
}

// ---------- dense node GEMM: Y[gy] = A @ W[gy], A split across two buffers ---
// A(k) = k < split ? A0[row][k] : A1[row][k-split]; lda = 128 for both.
__global__ __launch_bounds__(256) void k_gemm(
    const float* __restrict__ A0, const float* __restrict__ A1, int split,
    const float* __restrict__ W, float* __restrict__ Y, int M, int K) {
  __shared__ float sW[64][132];
  __shared__ float sX[64][68];
  const int t = threadIdx.x;
  const int gy = blockIdx.y;
  const int m0 = blockIdx.x * 64;
  const float* B = W + (size_t)gy * K * 128;
  float* C = Y + (size_t)gy * M * 128;
  const int le = t & 63;
  const int kg = t >> 6;
  const int eg = t & 15;
  const int cg = t >> 4;
  const int row = min(m0 + le, M - 1);

  float acc[4][8];
#pragma unroll
  for (int i = 0; i < 4; ++i)
#pragma unroll
    for (int j = 0; j < 8; ++j) acc[i][j] = 0.f;

  const int nchunk = K >> 6;
  for (int kc = 0; kc < nchunk; ++kc) {
    __syncthreads();
#pragma unroll
    for (int i = 0; i < 8; ++i) {
      int idx = (i * 256 + t) * 4;
      int kk = idx >> 7, cc = idx & 127;
      float4 w4 = *(const float4*)(B + (size_t)(kc * 64 + kk) * 128 + cc);
      *(float4*)&sW[kk][cc] = w4;
    }
#pragma unroll
    for (int i = 0; i < 4; ++i) {
      int kk = kg * 16 + i * 4;
      int kglob = kc * 64 + kk;
      const float* Ap = (kglob < split) ? (A0 + (size_t)row * 128 + kglob)
                                        : (A1 + (size_t)row * 128 + (kglob - split));
      float4 v = *(const float4*)Ap;
      sX[kk + 0][le] = v.x;
      sX[kk + 1][le] = v.y;
      sX[kk + 2][le] = v.z;
      sX[kk + 3][le] = v.w;
    }
    __syncthreads();
#pragma unroll 4
    for (int kk = 0; kk < 64; ++kk) {
      float4 xv = *(const float4*)&sX[kk][eg * 4];
      float4 wa = *(const float4*)&sW[kk][cg * 8];
      float4 wb = *(const float4*)&sW[kk][cg * 8 + 4];
      float xs[4] = {xv.x, xv.y, xv.z, xv.w};
      float ws[8] = {wa.x, wa.y, wa.z, wa.w, wb.x, wb.y, wb.z, wb.w};
#pragma unroll
      for (int i = 0; i < 4; ++i)
#pragma unroll
        for (int j = 0; j < 8; ++j) acc[i][j] = fmaf(xs[i], ws[j], acc[i][j]);
    }
  }
#pragma unroll
  for (int i = 0; i < 4; ++i) {
    int r = m0 + eg * 4 + i;
    if (r < M) {
#pragma unroll
      for (int j = 0; j < 8; ++j) C[(size_t)r * 128 + cg * 8 + j] = acc[i][j];
    }
  }
}

// ---------- prop: out[n] = norm[n] * sum_{e: dst=n} x[src[e]] * norm[src[e]] --
// one wave per node; lane handles a float2 (128 cols / 64 lanes)
__global__ __launch_bounds__(256) void k_prop(
    const float* __restrict__ x, float* __restrict__ out,
    const int* __restrict__ offs, const int* __restrict__ csr_src,
    const float* __restrict__ norm, int N) {
  const int node = blockIdx.x * 4 + (threadIdx.x >> 6);
  const int lane = threadIdx.x & 63;
  if (node >= N) return;
  const int b = offs[node], e = offs[node + 1];
  const float2* x2 = (const float2*)x;
  float ax = 0.f, ay = 0.f;
  for (int i = b; i < e; ++i) {
    int s = csr_src[i];
    float ns = norm[s];
    float2 v = x2[(size_t)s * 64 + lane];
    ax = fmaf(v.x, ns, ax);
    ay = fmaf(v.y, ns, ay);
  }
  float nn = norm[node];
  ((float2*)out)[(size_t)node * 64 + lane] = make_float2(ax * nn, ay * nn);
}

// ---------- combine: h = relu(ya + t1 + t3 + b) ----------
__global__ void k_combine(const float* __restrict__ ya, const float* __restrict__ t1,
                          const float* __restrict__ t3, const float* __restrict__ bias,
                          float* __restrict__ h, int total4) {
  int i = blockIdx.x * blockDim.x + threadIdx.x;
  int stride = gridDim.x * blockDim.x;
  const float4* A = (const float4*)ya;
  const float4* P = (const float4*)t1;
  const float4* Q = (const float4*)t3;
  const float4* Bv = (const float4*)bias;
  float4* H = (float4*)h;
  for (; i < total4; i += stride) {
    float4 a = A[i], p = P[i], q = Q[i], bb = Bv[i & 31];
    float4 r;
    r.x = a.x + p.x + q.x + bb.x;
    r.y = a.y + p.y + q.y + bb.y;
    r.z = a.z + p.z + q.z + bb.z;
    r.w = a.w + p.w + q.w + bb.w;
    r.x = r.x > 0.f ? r.x : 0.f;
    r.y = r.y > 0.f ? r.y : 0.f;
    r.z = r.z > 0.f ? r.z : 0.f;
    r.w = r.w > 0.f ? r.w : 0.f;
    H[i] = r;
  }
}

// ---------- column sums of h -> hg[128] ----------
__global__ void k_colsum(const float* __restrict__ h, float* __restrict__ hg, int N) {
  const int t = threadIdx.x;  // 128
  const int per = (N + gridDim.x - 1) / gridDim.x;
  const int n0 = blockIdx.x * per, n1 = min(n0 + per, N);
  float s = 0.f;
  for (int n = n0; n < n1; ++n) s += h[(size_t)n * 128 + t];
  unsafeAtomicAdd(&hg[t], s);
}

// ---------- final: out = (hg/N) . Wp + bp ----------
__global__ void k_final(const float* __restrict__ hg, const float* __restrict__ Wp,
                        const float* __restrict__ bp, float* __restrict__ out,
                        float invN) {
  __shared__ float red[128];
  const int t = threadIdx.x;
  red[t] = hg[t] * invN * Wp[t];
  __syncthreads();
  for (int s = 64; s > 0; s >>= 1) {
    if (t < s) red[t] += red[t + s];
    __syncthreads();
  }
  if (t == 0) out[0] = red[0] + bp[0];
}

extern "C" void kernel_launch(void* const* d_in, const int* in_sizes, int n_in,
                              void* d_out, int out_size, void* d_ws, size_t ws_size,
                              hipStream_t stream) {
  const float* node_fea = (const float*)d_in[0];
  const float* edge_fea = (const float*)d_in[1];
  const int* src = (const int*)d_in[2];
  const int* dst = (const int*)d_in[3];
  const float* msg_W = (const float*)d_in[4];
  const float* msg_b = (const float*)d_in[5];
  const float* W1 = (const float*)d_in[6];
  const float* b1 = (const float*)d_in[7];
  const float* W2 = (const float*)d_in[8];
  const float* b2 = (const float*)d_in[9];
  const float* Wp = (const float*)d_in[10];
  const float* bp = (const float*)d_in[11];

  const int N = in_sizes[0] / 128;  // 50000
  const int E = in_sizes[2];        // 1600000

  // workspace layout
  char* p = (char*)d_ws;
  auto alloc = [&](size_t bytes) {
    char* r = p;
    p += (bytes + 255) & ~(size_t)255;
    return r;
  };
  int* deg = (int*)alloc((size_t)N * 4);
  float* norm = (float*)alloc((size_t)N * 4);
  int* offs = (int*)alloc((size_t)(N + 1) * 4);
  int* cursor = (int*)alloc((size_t)N * 4);
  int* csr_src = (int*)alloc((size_t)E * 4);
  float* h_neigh = (float*)alloc((size_t)N * 128 * 4);  // reused as H2
  float* Y = (float*)alloc((size_t)3 * N * 128 * 4);    // YA|YB|YC
  float* T = (float*)alloc((size_t)N * 128 * 4);
  float* H = (float*)alloc((size_t)N * 128 * 4);
  float* hg = (float*)alloc(128 * 4);

  hipMemsetAsync(deg, 0, (size_t)N * 4, stream);
  hipMemsetAsync(h_neigh, 0, (size_t)N * 128 * 4, stream);
  hipMemsetAsync(hg, 0, 128 * 4, stream);

  // graph structure
  k_deg<<<2048, 256, 0, stream>>>(dst, deg, E);
  k_scan<<<1, 1024, 0, stream>>>(deg, norm, offs, cursor, N);
  k_csr<<<2048, 256, 0, stream>>>(src, dst, cursor, csr_src, E);

  // edge messages -> h_neigh
  k_edge_msg<<<E / 64, 256, 0, stream>>>(node_fea, edge_fea, src, dst, msg_W,
                                         msg_b, h_neigh);

  const size_t NH = (size_t)N * 128;
  dim3 g1((N + 63) / 64, 3);

  // layer 1: x = [node_fea | h_neigh] (split-A), K=256
  k_gemm<<<g1, 256, 0, stream>>>(node_fea, h_neigh, 128, W1, Y, N, 256);
  k_prop<<<N / 4, 256, 0, stream>>>(Y + NH, T, offs, csr_src, norm, N);           // T1 = prop(YB)
  k_prop<<<N / 4, 256, 0, stream>>>(Y + 2 * NH, Y + NH, offs, csr_src, norm, N);  // T2 = prop(YC)
  k_prop<<<N / 4, 256, 0, stream>>>(Y + NH, Y + 2 * NH, offs, csr_src, norm, N);  // T3 = prop(T2)
  k_combine<<<2048, 256, 0, stream>>>(Y, T, Y + 2 * NH, b1, H, N * 32);

  // layer 2: x = H, K=128
  k_gemm<<<g1, 256, 0, stream>>>(H, H, 128, W2, Y, N, 128);
  k_prop<<<N / 4, 256, 0, stream>>>(Y + NH, T, offs, csr_src, norm, N);
  k_prop<<<N / 4, 256, 0, stream>>>(Y + 2 * NH, Y + NH, offs, csr_src, norm, N);
  k_prop<<<N / 4, 256, 0, stream>>>(Y + NH, Y + 2 * NH, offs, csr_src, norm, N);
  k_combine<<<2048, 256, 0, stream>>>(Y, T, Y + 2 * NH, b2, h_neigh, N * 32);

  // readout
  k_colsum<<<256, 128, 0, stream>>>(h_neigh, hg, N);
  k_final<<<1, 128, 0, stream>>>(hg, Wp, bp, (float*)d_out, 1.0f / (float)N);
}

// Round 2
// 2092.121 us; speedup vs baseline: 3.3237x; 3.3237x over previous
//
#include <hip/hip_runtime.h>
#include <hip/hip_bf16.h>

// ---------------------------------------------------------------------------
// graphNN round 2:
//  - edge message GEMM in CSR(dst) order, bf16 hi/lo split MFMA (fp32-accurate)
//  - fused segment-sum epilogue (LDS walk) -> ~2 atomics/col/block, no msg buf
//  - node GEMMs / props / combine unchanged (fp32, known-correct from R1)
// ---------------------------------------------------------------------------

typedef __attribute__((ext_vector_type(8))) short short8;
typedef __attribute__((ext_vector_type(4))) float f32x4;

static __device__ __forceinline__ unsigned short f2bf(float x) {
  union { float f; unsigned u; } v{x};
  unsigned r = v.u + 0x7FFF + ((v.u >> 16) & 1);
  return (unsigned short)(r >> 16);
}
static __device__ __forceinline__ float bf2f(unsigned short h) {
  union { unsigned u; float f; } v{(unsigned)h << 16};
  return v.f;
}

// ---------- degree histogram ----------
__global__ void k_deg(const int* __restrict__ dst, int* __restrict__ deg, int E) {
  int i = blockIdx.x * blockDim.x + threadIdx.x;
  int stride = gridDim.x * blockDim.x;
  for (; i < E; i += stride) atomicAdd(&deg[dst[i]], 1);
}

// ---------- exclusive scan over deg -> offsets, cursor; also norm ----------
__global__ void k_scan(const int* __restrict__ deg, float* __restrict__ norm,
                       int* __restrict__ offs, int* __restrict__ cursor, int N) {
  __shared__ int part[1024];
  const int t = threadIdx.x;
  const int C = (N + 1023) >> 10;
  const int b = t * C, e = min(b + C, N);
  int s = 0;
  for (int i = b; i < e; ++i) s += deg[i];
  part[t] = s;
  __syncthreads();
  for (int ofs = 1; ofs < 1024; ofs <<= 1) {
    int v = (t >= ofs) ? part[t - ofs] : 0;
    __syncthreads();
    part[t] += v;
    __syncthreads();
  }
  int base = (t == 0) ? 0 : part[t - 1];
  for (int i = b; i < e; ++i) {
    offs[i] = base;
    cursor[i] = base;
    int d = deg[i];
    base += d;
    norm[i] = rsqrtf((float)max(d, 1));
  }
  if (t == 0) offs[N] = part[1023];
}

// ---------- CSR fill: srcnode, eid, pos->dstnode ----------
__global__ void k_csr(const int* __restrict__ src, const int* __restrict__ dst,
                      int* __restrict__ cursor, int* __restrict__ csr_srcnode,
                      int* __restrict__ csr_eid, int* __restrict__ pos2node, int E) {
  int i = blockIdx.x * blockDim.x + threadIdx.x;
  int stride = gridDim.x * blockDim.x;
  for (; i < E; i += stride) {
    int d = dst[i];
    int pos = atomicAdd(&cursor[d], 1);
    csr_srcnode[pos] = src[i];
    csr_eid[pos] = i;
    pos2node[pos] = d;
  }
}

// ---------- prep: msg_W [192][128] fp32 -> hi/lo bf16 in MFMA fragment order -
// flat id = (((kc*16 + nt*2 + ks)*64 + lane)*8 + j)
// k = kc*64 + ks*32 + (lane>>4)*8 + j ; col = nt*16 + (lane&15)
__global__ void k_prepW(const float* __restrict__ W, unsigned short* __restrict__ Wf_hi,
                        unsigned short* __restrict__ Wf_lo, int KC) {
  int id = blockIdx.x * 256 + threadIdx.x;
  if (id >= KC * 8192) return;
  int j = id & 7;
  int l = (id >> 3) & 63;
  int rest = id >> 9;
  int ks = rest & 1, nt = (rest >> 1) & 7, kc = rest >> 4;
  int k = kc * 64 + ks * 32 + (l >> 4) * 8 + j;
  int col = nt * 16 + (l & 15);
  float w = W[(size_t)k * 128 + col];
  unsigned short hi = f2bf(w);
  unsigned short lo = f2bf(w - bf2f(hi));
  Wf_hi[id] = hi;
  Wf_lo[id] = lo;
}

// ---------- edge message GEMM (CSR order) + fused segment-sum epilogue ------
// tile: 64 CSR rows x 128 cols, K=192 (3 chunks of 64). 4 waves, one 16-row
// M-tile each. hi/lo split bf16: C = Xhi@Whi + Xlo@Whi + Xhi@Wlo (fp32 acc).
__global__ __launch_bounds__(256) void k_edge_gemm(
    const float* __restrict__ nf, const float* __restrict__ ef,
    const int* __restrict__ csr_srcnode, const int* __restrict__ csr_eid,
    const int* __restrict__ pos2node, const unsigned short* __restrict__ Wf_hi,
    const unsigned short* __restrict__ Wf_lo, const float* __restrict__ bias,
    float* __restrict__ h_neigh) {
  // LDS layout: [0,8K) Xhi  [8K,16K) Xlo  [16K,48K) Whi|Wlo
  // epilogue overlay: Cs (64 x stride132 f32 = 33792B) at 16K; sNode over Xhi
  __shared__ __align__(16) char lds[50176];
  unsigned short* Xhi = (unsigned short*)lds;
  unsigned short* Xlo = (unsigned short*)(lds + 8192);
  unsigned short* Whi = (unsigned short*)(lds + 16384);
  unsigned short* Wlo = (unsigned short*)(lds + 32768);
  float* Cs = (float*)(lds + 16384);
  int* sNode = (int*)lds;

  const int t = threadIdx.x;
  const int b0 = blockIdx.x * 64;
  const int l = t & 63;   // lane within wave
  const int mt = t >> 6;  // wave id == M-tile
  // staging coords: 4 threads per row, 16 k each (2 octets)
  const int sr = t & 63;
  const int sq = t >> 6;
  const int srcn = csr_srcnode[b0 + sr];
  const int eid = csr_eid[b0 + sr];

  f32x4 acc[8];
#pragma unroll
  for (int nt = 0; nt < 8; ++nt) acc[nt] = (f32x4){0.f, 0.f, 0.f, 0.f};

  for (int kc = 0; kc < 3; ++kc) {
    __syncthreads();
    // --- stage W chunk (fragment order, pure linear copy: 1024+1024 x 16B) ---
    {
      const ulong2* gh = (const ulong2*)Wf_hi + (size_t)kc * 1024;
      const ulong2* gl = (const ulong2*)Wf_lo + (size_t)kc * 1024;
      ulong2* lh = (ulong2*)Whi;
      ulong2* ll = (ulong2*)Wlo;
#pragma unroll
      for (int i = 0; i < 4; ++i) {
        lh[i * 256 + t] = gh[i * 256 + t];
        ll[i * 256 + t] = gl[i * 256 + t];
      }
    }
    // --- stage X chunk: gather fp32 row, convert hi/lo, swizzled b128 writes -
    {
      const float* rowp = (kc < 2) ? (nf + (size_t)srcn * 128 + kc * 64 + sq * 16)
                                   : (ef + (size_t)eid * 64 + sq * 16);
#pragma unroll
      for (int i2 = 0; i2 < 2; ++i2) {
        const int o = sq * 2 + i2;  // k-octet within chunk (0..7)
        float4 a = *(const float4*)(rowp + i2 * 8);
        float4 b = *(const float4*)(rowp + i2 * 8 + 4);
        float tmp[8] = {a.x, a.y, a.z, a.w, b.x, b.y, b.z, b.w};
        short8 vh, vl;
#pragma unroll
        for (int j = 0; j < 8; ++j) {
          unsigned short h = f2bf(tmp[j]);
          vh[j] = (short)h;
          vl[j] = (short)f2bf(tmp[j] - bf2f(h));
        }
        const int slot = (sr >> 4) * 128 + o * 16 + (sr & 15);
        *(short8*)(Xhi + (size_t)slot * 8) = vh;
        *(short8*)(Xlo + (size_t)slot * 8) = vl;
      }
    }
    __syncthreads();
    // --- MFMA: per wave 2 K-steps x 8 N-tiles x 3 products ---
    const short8* Xh8 = (const short8*)Xhi;
    const short8* Xl8 = (const short8*)Xlo;
    const short8* Wh8 = (const short8*)Whi;
    const short8* Wl8 = (const short8*)Wlo;
#pragma unroll
    for (int ks = 0; ks < 2; ++ks) {
      short8 ah = Xh8[mt * 128 + ks * 64 + l];
      short8 al = Xl8[mt * 128 + ks * 64 + l];
#pragma unroll
      for (int nt = 0; nt < 8; ++nt) {
        short8 bh = Wh8[(nt * 2 + ks) * 64 + l];
        short8 bl = Wl8[(nt * 2 + ks) * 64 + l];
        acc[nt] = __builtin_amdgcn_mfma_f32_16x16x32_bf16(ah, bh, acc[nt], 0, 0, 0);
        acc[nt] = __builtin_amdgcn_mfma_f32_16x16x32_bf16(al, bh, acc[nt], 0, 0, 0);
        acc[nt] = __builtin_amdgcn_mfma_f32_16x16x32_bf16(ah, bl, acc[nt], 0, 0, 0);
      }
    }
  }
  __syncthreads();
  // --- write C tile to LDS (over W region), stride 132 to dodge conflicts ---
#pragma unroll
  for (int nt = 0; nt < 8; ++nt)
#pragma unroll
    for (int rg = 0; rg < 4; ++rg)
      Cs[(mt * 16 + (l >> 4) * 4 + rg) * 132 + nt * 16 + (l & 15)] = acc[nt][rg];
  if (t < 64) sNode[t] = pos2node[b0 + t];
  __syncthreads();
  // --- segment walk: dst sorted within tile -> few atomics ---
  if (t < 128) {
    const int col = t;
    const float bj = bias[col];
    int node = sNode[0];
    float s = fmaxf(Cs[col] + bj, 0.f);
    for (int r = 1; r < 64; ++r) {
      int n2 = sNode[r];
      float v = fmaxf(Cs[r * 132 + col] + bj, 0.f);
      if (n2 == node) {
        s += v;
      } else {
        unsafeAtomicAdd(&h_neigh[(size_t)node * 128 + col], s);
        node = n2;
        s = v;
      }
    }
    unsafeAtomicAdd(&h_neigh[(size_t)node * 128 + col], s);
  }
}

// ---------- dense node GEMM (fp32): Y[gy] = A @ W[gy], split-A --------------
__global__ __launch_bounds__(256) void k_gemm(
    const float* __restrict__ A0, const float* __restrict__ A1, int split,
    const float* __restrict__ W, float* __restrict__ Y, int M, int K) {
  __shared__ float sW[64][132];
  __shared__ float sX[64][68];
  const int t = threadIdx.x;
  const int gy = blockIdx.y;
  const int m0 = blockIdx.x * 64;
  const float* B = W + (size_t)gy * K * 128;
  float* C = Y + (size_t)gy * M * 128;
  const int le = t & 63;
  const int kg = t >> 6;
  const int eg = t & 15;
  const int cg = t >> 4;
  const int row = min(m0 + le, M - 1);

  float acc[4][8];
#pragma unroll
  for (int i = 0; i < 4; ++i)
#pragma unroll
    for (int j = 0; j < 8; ++j) acc[i][j] = 0.f;

  const int nchunk = K >> 6;
  for (int kc = 0; kc < nchunk; ++kc) {
    __syncthreads();
#pragma unroll
    for (int i = 0; i < 8; ++i) {
      int idx = (i * 256 + t) * 4;
      int kk = idx >> 7, cc = idx & 127;
      float4 w4 = *(const float4*)(B + (size_t)(kc * 64 + kk) * 128 + cc);
      *(float4*)&sW[kk][cc] = w4;
    }
#pragma unroll
    for (int i = 0; i < 4; ++i) {
      int kk = kg * 16 + i * 4;
      int kglob = kc * 64 + kk;
      const float* Ap = (kglob < split) ? (A0 + (size_t)row * 128 + kglob)
                                        : (A1 + (size_t)row * 128 + (kglob - split));
      float4 v = *(const float4*)Ap;
      sX[kk + 0][le] = v.x;
      sX[kk + 1][le] = v.y;
      sX[kk + 2][le] = v.z;
      sX[kk + 3][le] = v.w;
    }
    __syncthreads();
#pragma unroll 4
    for (int kk = 0; kk < 64; ++kk) {
      float4 xv = *(const float4*)&sX[kk][eg * 4];
      float4 wa = *(const float4*)&sW[kk][cg * 8];
      float4 wb = *(const float4*)&sW[kk][cg * 8 + 4];
      float xs[4] = {xv.x, xv.y, xv.z, xv.w};
      float ws[8] = {wa.x, wa.y, wa.z, wa.w, wb.x, wb.y, wb.z, wb.w};
#pragma unroll
      for (int i = 0; i < 4; ++i)
#pragma unroll
        for (int j = 0; j < 8; ++j) acc[i][j] = fmaf(xs[i], ws[j], acc[i][j]);
    }
  }
#pragma unroll
  for (int i = 0; i < 4; ++i) {
    int r = m0 + eg * 4 + i;
    if (r < M) {
#pragma unroll
      for (int j = 0; j < 8; ++j) C[(size_t)r * 128 + cg * 8 + j] = acc[i][j];
    }
  }
}

// ---------- prop: out[n] = norm[n] * sum_{e: dst=n} x[src[e]] * norm[src[e]] -
__global__ __launch_bounds__(256) void k_prop(
    const float* __restrict__ x, float* __restrict__ out,
    const int* __restrict__ offs, const int* __restrict__ csr_src,
    const float* __restrict__ norm, int N) {
  const int node = blockIdx.x * 4 + (threadIdx.x >> 6);
  const int lane = threadIdx.x & 63;
  if (node >= N) return;
  const int b = offs[node], e = offs[node + 1];
  const float2* x2 = (const float2*)x;
  float ax = 0.f, ay = 0.f;
  for (int i = b; i < e; ++i) {
    int s = csr_src[i];
    float ns = norm[s];
    float2 v = x2[(size_t)s * 64 + lane];
    ax = fmaf(v.x, ns, ax);
    ay = fmaf(v.y, ns, ay);
  }
  float nn = norm[node];
  ((float2*)out)[(size_t)node * 64 + lane] = make_float2(ax * nn, ay * nn);
}

// ---------- combine: h = relu(ya + t1 + t3 + b) ----------
__global__ void k_combine(const float* __restrict__ ya, const float* __restrict__ t1,
                          const float* __restrict__ t3, const float* __restrict__ bias,
                          float* __restrict__ h, int total4) {
  int i = blockIdx.x * blockDim.x + threadIdx.x;
  int stride = gridDim.x * blockDim.x;
  const float4* A = (const float4*)ya;
  const float4* P = (const float4*)t1;
  const float4* Q = (const float4*)t3;
  const float4* Bv = (const float4*)bias;
  float4* H = (float4*)h;
  for (; i < total4; i += stride) {
    float4 a = A[i], p = P[i], q = Q[i], bb = Bv[i & 31];
    float4 r;
    r.x = a.x + p.x + q.x + bb.x;
    r.y = a.y + p.y + q.y + bb.y;
    r.z = a.z + p.z + q.z + bb.z;
    r.w = a.w + p.w + q.w + bb.w;
    r.x = r.x > 0.f ? r.x : 0.f;
    r.y = r.y > 0.f ? r.y : 0.f;
    r.z = r.z > 0.f ? r.z : 0.f;
    r.w = r.w > 0.f ? r.w : 0.f;
    H[i] = r;
  }
}

// ---------- column sums of h -> hg[128] ----------
__global__ void k_colsum(const float* __restrict__ h, float* __restrict__ hg, int N) {
  const int t = threadIdx.x;  // 128
  const int per = (N + gridDim.x - 1) / gridDim.x;
  const int n0 = blockIdx.x * per, n1 = min(n0 + per, N);
  float s = 0.f;
  for (int n = n0; n < n1; ++n) s += h[(size_t)n * 128 + t];
  unsafeAtomicAdd(&hg[t], s);
}

// ---------- final: out = (hg/N) . Wp + bp ----------
__global__ void k_final(const float* __restrict__ hg, const float* __restrict__ Wp,
                        const float* __restrict__ bp, float* __restrict__ out,
                        float invN) {
  __shared__ float red[128];
  const int t = threadIdx.x;
  red[t] = hg[t] * invN * Wp[t];
  __syncthreads();
  for (int s = 64; s > 0; s >>= 1) {
    if (t < s) red[t] += red[t + s];
    __syncthreads();
  }
  if (t == 0) out[0] = red[0] + bp[0];
}

extern "C" void kernel_launch(void* const* d_in, const int* in_sizes, int n_in,
                              void* d_out, int out_size, void* d_ws, size_t ws_size,
                              hipStream_t stream) {
  const float* node_fea = (const float*)d_in[0];
  const float* edge_fea = (const float*)d_in[1];
  const int* src = (const int*)d_in[2];
  const int* dst = (const int*)d_in[3];
  const float* msg_W = (const float*)d_in[4];
  const float* msg_b = (const float*)d_in[5];
  const float* W1 = (const float*)d_in[6];
  const float* b1 = (const float*)d_in[7];
  const float* W2 = (const float*)d_in[8];
  const float* b2 = (const float*)d_in[9];
  const float* Wp = (const float*)d_in[10];
  const float* bp = (const float*)d_in[11];

  const int N = in_sizes[0] / 128;  // 50000
  const int E = in_sizes[2];        // 1600000

  char* p = (char*)d_ws;
  auto alloc = [&](size_t bytes) {
    char* r = p;
    p += (bytes + 255) & ~(size_t)255;
    return r;
  };
  int* deg = (int*)alloc((size_t)N * 4);
  float* norm = (float*)alloc((size_t)N * 4);
  int* offs = (int*)alloc((size_t)(N + 1) * 4);
  int* cursor = (int*)alloc((size_t)N * 4);
  int* csr_srcnode = (int*)alloc((size_t)E * 4);
  int* csr_eid = (int*)alloc((size_t)E * 4);
  int* pos2node = (int*)alloc((size_t)E * 4);
  unsigned short* Wf_hi = (unsigned short*)alloc(3 * 8192 * 2);
  unsigned short* Wf_lo = (unsigned short*)alloc(3 * 8192 * 2);
  float* h_neigh = (float*)alloc((size_t)N * 128 * 4);  // reused as H2
  float* Y = (float*)alloc((size_t)3 * N * 128 * 4);    // YA|YB|YC
  float* T = (float*)alloc((size_t)N * 128 * 4);
  float* H = (float*)alloc((size_t)N * 128 * 4);
  float* hg = (float*)alloc(128 * 4);

  hipMemsetAsync(deg, 0, (size_t)N * 4, stream);
  hipMemsetAsync(h_neigh, 0, (size_t)N * 128 * 4, stream);
  hipMemsetAsync(hg, 0, 128 * 4, stream);

  // graph structure + W prep
  k_deg<<<2048, 256, 0, stream>>>(dst, deg, E);
  k_scan<<<1, 1024, 0, stream>>>(deg, norm, offs, cursor, N);
  k_csr<<<2048, 256, 0, stream>>>(src, dst, cursor, csr_srcnode, csr_eid, pos2node, E);
  k_prepW<<<96, 256, 0, stream>>>(msg_W, Wf_hi, Wf_lo, 3);

  // edge messages -> h_neigh (fused GEMM + segment-sum)
  k_edge_gemm<<<E / 64, 256, 0, stream>>>(node_fea, edge_fea, csr_srcnode, csr_eid,
                                          pos2node, Wf_hi, Wf_lo, msg_b, h_neigh);

  const size_t NH = (size_t)N * 128;
  dim3 g1((N + 63) / 64, 3);

  // layer 1: x = [node_fea | h_neigh] (split-A), K=256
  k_gemm<<<g1, 256, 0, stream>>>(node_fea, h_neigh, 128, W1, Y, N, 256);
  k_prop<<<N / 4, 256, 0, stream>>>(Y + NH, T, offs, csr_srcnode, norm, N);
  k_prop<<<N / 4, 256, 0, stream>>>(Y + 2 * NH, Y + NH, offs, csr_srcnode, norm, N);
  k_prop<<<N / 4, 256, 0, stream>>>(Y + NH, Y + 2 * NH, offs, csr_srcnode, norm, N);
  k_combine<<<2048, 256, 0, stream>>>(Y, T, Y + 2 * NH, b1, H, N * 32);

  // layer 2: x = H, K=128
  k_gemm<<<g1, 256, 0, stream>>>(H, H, 128, W2, Y, N, 128);
  k_prop<<<N / 4, 256, 0, stream>>>(Y + NH, T, offs, csr_srcnode, norm, N);
  k_prop<<<N / 4, 256, 0, stream>>>(Y + 2 * NH, Y + NH, offs, csr_srcnode, norm, N);
  k_prop<<<N / 4, 256, 0, stream>>>(Y + NH, Y + 2 * NH, offs, csr_srcnode, norm, N);
  k_combine<<<2048, 256, 0, stream>>>(Y, T, Y + 2 * NH, b2, h_neigh, N * 32);

  // readout
  k_colsum<<<256, 128, 0, stream>>>(h_neigh, hg, N);
  k_final<<<1, 128, 0, stream>>>(hg, Wp, bp, (float*)d_out, 1.0f / (float)N);
}

// Round 3
// 1864.478 us; speedup vs baseline: 3.7295x; 1.1221x over previous
//
#include <hip/hip_runtime.h>
#include <hip/hip_bf16.h>

// ---------------------------------------------------------------------------
// graphNN round 3:
//  - edge GEMM split: Z = nf@W_top + b precomputed per node (K=192 -> K=64);
//    Z[src] added in epilogue (coalesced, L3-resident)
//  - all dense GEMMs on MFMA (bf16 hi/lo 3-product, fp32-accurate)
//  - norm folded into GEMM epilogue; dual-prop single pass; combine fused
//    into second prop pass
// ---------------------------------------------------------------------------

typedef __attribute__((ext_vector_type(8))) short short8;
typedef __attribute__((ext_vector_type(4))) float f32x4;

static __device__ __forceinline__ unsigned short f2bf(float x) {
  union { float f; unsigned u; } v{x};
  unsigned r = v.u + 0x7FFF + ((v.u >> 16) & 1);
  return (unsigned short)(r >> 16);
}
static __device__ __forceinline__ float bf2f(unsigned short h) {
  union { unsigned u; float f; } v{(unsigned)h << 16};
  return v.f;
}

// ---------- degree histogram ----------
__global__ void k_deg(const int* __restrict__ dst, int* __restrict__ deg, int E) {
  int i = blockIdx.x * blockDim.x + threadIdx.x;
  int stride = gridDim.x * blockDim.x;
  for (; i < E; i += stride) atomicAdd(&deg[dst[i]], 1);
}

// ---------- exclusive scan over deg -> offsets, cursor; also norm ----------
__global__ void k_scan(const int* __restrict__ deg, float* __restrict__ norm,
                       int* __restrict__ offs, int* __restrict__ cursor, int N) {
  __shared__ int part[1024];
  const int t = threadIdx.x;
  const int C = (N + 1023) >> 10;
  const int b = t * C, e = min(b + C, N);
  int s = 0;
  for (int i = b; i < e; ++i) s += deg[i];
  part[t] = s;
  __syncthreads();
  for (int ofs = 1; ofs < 1024; ofs <<= 1) {
    int v = (t >= ofs) ? part[t - ofs] : 0;
    __syncthreads();
    part[t] += v;
    __syncthreads();
  }
  int base = (t == 0) ? 0 : part[t - 1];
  for (int i = b; i < e; ++i) {
    offs[i] = base;
    cursor[i] = base;
    int d = deg[i];
    base += d;
    norm[i] = rsqrtf((float)max(d, 1));
  }
  if (t == 0) offs[N] = part[1023];
}

// ---------- CSR fill: srcnode, eid, pos->dstnode ----------
__global__ void k_csr(const int* __restrict__ src, const int* __restrict__ dst,
                      int* __restrict__ cursor, int* __restrict__ csr_srcnode,
                      int* __restrict__ csr_eid, int* __restrict__ pos2node, int E) {
  int i = blockIdx.x * blockDim.x + threadIdx.x;
  int stride = gridDim.x * blockDim.x;
  for (; i < E; i += stride) {
    int d = dst[i];
    int pos = atomicAdd(&cursor[d], 1);
    csr_srcnode[pos] = src[i];
    csr_eid[pos] = i;
    pos2node[pos] = d;
  }
}

// ---------- prep: W [K][128] fp32 -> hi/lo bf16 in MFMA fragment order ------
// flat id = (((kc*16 + nt*2 + ks)*64 + lane)*8 + j)
// k = kc*64 + ks*32 + (lane>>4)*8 + j ; col = nt*16 + (lane&15)
__global__ void k_prepW(const float* __restrict__ W, unsigned short* __restrict__ Wf_hi,
                        unsigned short* __restrict__ Wf_lo, int KC) {
  int id = blockIdx.x * 256 + threadIdx.x;
  if (id >= KC * 8192) return;
  int j = id & 7;
  int l = (id >> 3) & 63;
  int rest = id >> 9;
  int ks = rest & 1, nt = (rest >> 1) & 7, kc = rest >> 4;
  int k = kc * 64 + ks * 32 + (l >> 4) * 8 + j;
  int col = nt * 16 + (l & 15);
  float w = W[(size_t)k * 128 + col];
  unsigned short hi = f2bf(w);
  unsigned short lo = f2bf(w - bf2f(hi));
  Wf_hi[id] = hi;
  Wf_lo[id] = lo;
}

// ---------- unified MFMA GEMM: out[gy] = A @ Wslice[gy] --------------------
// A(row,k) = (k/64 < split64) ? A0[row*128+k] : A1[row*128+k-split64*64]
// gy==0: outA[row*128+col] (+bias);  gy>0: outBC[row*256+(gy-1)*128+col] * n[row]
__global__ __launch_bounds__(256) void k_mm(
    const float* __restrict__ A0, const float* __restrict__ A1, int split64,
    const unsigned short* __restrict__ Wf_hi, const unsigned short* __restrict__ Wf_lo,
    const float* __restrict__ bias, const float* __restrict__ rowscale,
    float* __restrict__ outA, float* __restrict__ outBC, int M, int KC) {
  __shared__ __align__(16) char lds[49152];
  unsigned short* Xhi = (unsigned short*)lds;
  unsigned short* Xlo = (unsigned short*)(lds + 8192);
  unsigned short* Whi = (unsigned short*)(lds + 16384);
  unsigned short* Wlo = (unsigned short*)(lds + 32768);

  const int t = threadIdx.x;
  const int gy = blockIdx.y;
  const int m0 = blockIdx.x * 64;
  const int l = t & 63, mt = t >> 6;
  const int sr = t & 63, sq = t >> 6;
  const int row = min(m0 + sr, M - 1);
  const unsigned short* WH = Wf_hi + (size_t)gy * KC * 8192;
  const unsigned short* WL = Wf_lo + (size_t)gy * KC * 8192;

  f32x4 acc[8];
#pragma unroll
  for (int nt = 0; nt < 8; ++nt) acc[nt] = (f32x4){0.f, 0.f, 0.f, 0.f};

  for (int kc = 0; kc < KC; ++kc) {
    __syncthreads();
    {  // stage W chunk (fragment order, linear copy)
      const ulong2* gh = (const ulong2*)(WH + (size_t)kc * 8192);
      const ulong2* gl = (const ulong2*)(WL + (size_t)kc * 8192);
#pragma unroll
      for (int i = 0; i < 4; ++i) {
        ((ulong2*)Whi)[i * 256 + t] = gh[i * 256 + t];
        ((ulong2*)Wlo)[i * 256 + t] = gl[i * 256 + t];
      }
    }
    {  // stage A chunk hi/lo
      const float* base = (kc < split64) ? (A0 + (size_t)row * 128 + kc * 64)
                                         : (A1 + (size_t)row * 128 + (kc - split64) * 64);
#pragma unroll
      for (int i2 = 0; i2 < 2; ++i2) {
        const int o = sq * 2 + i2;
        float4 a4 = *(const float4*)(base + sq * 16 + i2 * 8);
        float4 b4 = *(const float4*)(base + sq * 16 + i2 * 8 + 4);
        float tmp[8] = {a4.x, a4.y, a4.z, a4.w, b4.x, b4.y, b4.z, b4.w};
        short8 vh, vl;
#pragma unroll
        for (int j = 0; j < 8; ++j) {
          unsigned short h = f2bf(tmp[j]);
          vh[j] = (short)h;
          vl[j] = (short)f2bf(tmp[j] - bf2f(h));
        }
        const int slot = (sr >> 4) * 128 + o * 16 + (sr & 15);
        *(short8*)(Xhi + (size_t)slot * 8) = vh;
        *(short8*)(Xlo + (size_t)slot * 8) = vl;
      }
    }
    __syncthreads();
    const short8* Xh8 = (const short8*)Xhi;
    const short8* Xl8 = (const short8*)Xlo;
    const short8* Wh8 = (const short8*)Whi;
    const short8* Wl8 = (const short8*)Wlo;
#pragma unroll
    for (int ks = 0; ks < 2; ++ks) {
      short8 ah = Xh8[mt * 128 + ks * 64 + l];
      short8 al = Xl8[mt * 128 + ks * 64 + l];
#pragma unroll
      for (int nt = 0; nt < 8; ++nt) {
        short8 bh = Wh8[(nt * 2 + ks) * 64 + l];
        short8 bl = Wl8[(nt * 2 + ks) * 64 + l];
        acc[nt] = __builtin_amdgcn_mfma_f32_16x16x32_bf16(ah, bh, acc[nt], 0, 0, 0);
        acc[nt] = __builtin_amdgcn_mfma_f32_16x16x32_bf16(al, bh, acc[nt], 0, 0, 0);
        acc[nt] = __builtin_amdgcn_mfma_f32_16x16x32_bf16(ah, bl, acc[nt], 0, 0, 0);
      }
    }
  }
  // epilogue: direct global store
  const int l15 = l & 15, lh = l >> 4;
#pragma unroll
  for (int nt = 0; nt < 8; ++nt) {
    const int col = nt * 16 + l15;
#pragma unroll
    for (int rg = 0; rg < 4; ++rg) {
      const int r = m0 + mt * 16 + lh * 4 + rg;
      if (r < M) {
        float v = acc[nt][rg];
        if (gy == 0) {
          if (bias) v += bias[col];
          outA[(size_t)r * 128 + col] = v;
        } else {
          outBC[(size_t)r * 256 + (gy - 1) * 128 + col] = v * rowscale[r];
        }
      }
    }
  }
}

// ---------- edge GEMM (K=64) + Z[src] add + relu + segment-sum epilogue -----
__global__ __launch_bounds__(256) void k_edge(
    const float* __restrict__ ef, const int* __restrict__ csr_srcnode,
    const int* __restrict__ csr_eid, const int* __restrict__ pos2node,
    const unsigned short* __restrict__ WBf_hi, const unsigned short* __restrict__ WBf_lo,
    const float* __restrict__ Z, float* __restrict__ h_neigh) {
  __shared__ __align__(16) char lds[49664];
  unsigned short* Xhi = (unsigned short*)lds;            // 8K
  unsigned short* Xlo = (unsigned short*)(lds + 8192);   // 8K
  unsigned short* Whi = (unsigned short*)(lds + 16384);  // 16K
  unsigned short* Wlo = (unsigned short*)(lds + 32768);  // 16K
  float* Cs = (float*)(lds + 16384);                     // 32K overlay (epilogue)
  int* sSrc = (int*)(lds + 49152);
  int* sNode = (int*)(lds + 49408);

  const int t = threadIdx.x;
  const int b0 = blockIdx.x * 64;
  const int l = t & 63, mt = t >> 6;
  const int sr = t & 63, sq = t >> 6;

  if (t < 64) {
    sSrc[t] = csr_srcnode[b0 + t];
    sNode[t] = pos2node[b0 + t];
  }
  const int eid = csr_eid[b0 + sr];

  {  // stage W_bot (single chunk, fragment order)
    const ulong2* gh = (const ulong2*)WBf_hi;
    const ulong2* gl = (const ulong2*)WBf_lo;
#pragma unroll
    for (int i = 0; i < 4; ++i) {
      ((ulong2*)Whi)[i * 256 + t] = gh[i * 256 + t];
      ((ulong2*)Wlo)[i * 256 + t] = gl[i * 256 + t];
    }
  }
  {  // stage ef row hi/lo
    const float* rowp = ef + (size_t)eid * 64 + sq * 16;
#pragma unroll
    for (int i2 = 0; i2 < 2; ++i2) {
      const int o = sq * 2 + i2;
      float4 a4 = *(const float4*)(rowp + i2 * 8);
      float4 b4 = *(const float4*)(rowp + i2 * 8 + 4);
      float tmp[8] = {a4.x, a4.y, a4.z, a4.w, b4.x, b4.y, b4.z, b4.w};
      short8 vh, vl;
#pragma unroll
      for (int j = 0; j < 8; ++j) {
        unsigned short h = f2bf(tmp[j]);
        vh[j] = (short)h;
        vl[j] = (short)f2bf(tmp[j] - bf2f(h));
      }
      const int slot = (sr >> 4) * 128 + o * 16 + (sr & 15);
      *(short8*)(Xhi + (size_t)slot * 8) = vh;
      *(short8*)(Xlo + (size_t)slot * 8) = vl;
    }
  }
  __syncthreads();

  f32x4 acc[8];
#pragma unroll
  for (int nt = 0; nt < 8; ++nt) acc[nt] = (f32x4){0.f, 0.f, 0.f, 0.f};
  {
    const short8* Xh8 = (const short8*)Xhi;
    const short8* Xl8 = (const short8*)Xlo;
    const short8* Wh8 = (const short8*)Whi;
    const short8* Wl8 = (const short8*)Wlo;
#pragma unroll
    for (int ks = 0; ks < 2; ++ks) {
      short8 ah = Xh8[mt * 128 + ks * 64 + l];
      short8 al = Xl8[mt * 128 + ks * 64 + l];
#pragma unroll
      for (int nt = 0; nt < 8; ++nt) {
        short8 bh = Wh8[(nt * 2 + ks) * 64 + l];
        short8 bl = Wl8[(nt * 2 + ks) * 64 + l];
        acc[nt] = __builtin_amdgcn_mfma_f32_16x16x32_bf16(ah, bh, acc[nt], 0, 0, 0);
        acc[nt] = __builtin_amdgcn_mfma_f32_16x16x32_bf16(al, bh, acc[nt], 0, 0, 0);
        acc[nt] = __builtin_amdgcn_mfma_f32_16x16x32_bf16(ah, bl, acc[nt], 0, 0, 0);
      }
    }
  }
  __syncthreads();
  // write C tile to LDS, XOR-swizzled (64 rows x 128 cols, no pad)
  const int l15 = l & 15, lh = l >> 4;
#pragma unroll
  for (int nt = 0; nt < 8; ++nt) {
#pragma unroll
    for (int rg = 0; rg < 4; ++rg) {
      const int row = mt * 16 + lh * 4 + rg;
      const int col = nt * 16 + l15;
      Cs[row * 128 + (col ^ ((row & 7) << 4))] = acc[nt][rg];
    }
  }
  __syncthreads();
  // segment walk with Z[src] add (1-deep prefetch)
  if (t < 128) {
    const int col = t;
    int node = sNode[0];
    float z = Z[(size_t)sSrc[0] * 128 + col];
    float zn = Z[(size_t)sSrc[1] * 128 + col];
    float s = fmaxf(Cs[col] + z, 0.f);
    for (int r = 1; r < 64; ++r) {
      z = zn;
      if (r < 63) zn = Z[(size_t)sSrc[r + 1] * 128 + col];
      float v = fmaxf(Cs[r * 128 + (col ^ ((r & 7) << 4))] + z, 0.f);
      int n2 = sNode[r];
      if (n2 == node) {
        s += v;
      } else {
        unsafeAtomicAdd(&h_neigh[(size_t)node * 128 + col], s);
        node = n2;
        s = v;
      }
    }
    unsafeAtomicAdd(&h_neigh[(size_t)node * 128 + col], s);
  }
}

// ---------- dual prop: comb [N][256] = [YB~|YC~] (pre-scaled by n[src]) -----
// T1[v] = n[v] * sum YB~[src];  T2s[v] = n[v]^2 * sum YC~[src]
__global__ __launch_bounds__(256) void k_prop2(
    const float* __restrict__ comb, const int* __restrict__ offs,
    const int* __restrict__ csr_src, const float* __restrict__ norm,
    float* __restrict__ T1, float* __restrict__ T2, int N) {
  const int v = blockIdx.x * 4 + (threadIdx.x >> 6);
  const int lane = threadIdx.x & 63;
  if (v >= N) return;
  const int b = offs[v], e = offs[v + 1];
  const float4* c4 = (const float4*)comb;
  float4 a = make_float4(0.f, 0.f, 0.f, 0.f);
  for (int i = b; i < e; ++i) {
    int s = csr_src[i];
    float4 x = c4[(size_t)s * 64 + lane];
    a.x += x.x;
    a.y += x.y;
    a.z += x.z;
    a.w += x.w;
  }
  float n = norm[v];
  float sc = (lane < 32) ? n : n * n;
  a.x *= sc;
  a.y *= sc;
  a.z *= sc;
  a.w *= sc;
  float* outp = (lane < 32) ? (T1 + (size_t)v * 128 + lane * 4)
                            : (T2 + (size_t)v * 128 + (lane - 32) * 4);
  *(float4*)outp = a;
}

// ---------- prop + combine: H[v] = relu(YA[v] + T1[v] + n[v]*sum T2s[src] + b)
__global__ __launch_bounds__(256) void k_propc(
    const float* __restrict__ T2s, const float* __restrict__ YA,
    const float* __restrict__ T1, const float* __restrict__ bias,
    const int* __restrict__ offs, const int* __restrict__ csr_src,
    const float* __restrict__ norm, float* __restrict__ H, int N) {
  const int v = blockIdx.x * 4 + (threadIdx.x >> 6);
  const int lane = threadIdx.x & 63;
  if (v >= N) return;
  const int b = offs[v], e = offs[v + 1];
  const float2* t2 = (const float2*)T2s;
  float ax = 0.f, ay = 0.f;
  for (int i = b; i < e; ++i) {
    int s = csr_src[i];
    float2 x = t2[(size_t)s * 64 + lane];
    ax += x.x;
    ay += x.y;
  }
  float n = norm[v];
  float2 ya = ((const float2*)YA)[(size_t)v * 64 + lane];
  float2 t1 = ((const float2*)T1)[(size_t)v * 64 + lane];
  float2 bb = ((const float2*)bias)[lane];
  float hx = ya.x + t1.x + n * ax + bb.x;
  float hy = ya.y + t1.y + n * ay + bb.y;
  hx = hx > 0.f ? hx : 0.f;
  hy = hy > 0.f ? hy : 0.f;
  ((float2*)H)[(size_t)v * 64 + lane] = make_float2(hx, hy);
}

// ---------- column sums of h -> hg[128] ----------
__global__ void k_colsum(const float* __restrict__ h, float* __restrict__ hg, int N) {
  const int t = threadIdx.x;  // 128
  const int per = (N + gridDim.x - 1) / gridDim.x;
  const int n0 = blockIdx.x * per, n1 = min(n0 + per, N);
  float s = 0.f;
  for (int n = n0; n < n1; ++n) s += h[(size_t)n * 128 + t];
  unsafeAtomicAdd(&hg[t], s);
}

// ---------- final: out = (hg/N) . Wp + bp ----------
__global__ void k_final(const float* __restrict__ hg, const float* __restrict__ Wp,
                        const float* __restrict__ bp, float* __restrict__ out,
                        float invN) {
  __shared__ float red[128];
  const int t = threadIdx.x;
  red[t] = hg[t] * invN * Wp[t];
  __syncthreads();
  for (int s = 64; s > 0; s >>= 1) {
    if (t < s) red[t] += red[t + s];
    __syncthreads();
  }
  if (t == 0) out[0] = red[0] + bp[0];
}

extern "C" void kernel_launch(void* const* d_in, const int* in_sizes, int n_in,
                              void* d_out, int out_size, void* d_ws, size_t ws_size,
                              hipStream_t stream) {
  const float* node_fea = (const float*)d_in[0];
  const float* edge_fea = (const float*)d_in[1];
  const int* src = (const int*)d_in[2];
  const int* dst = (const int*)d_in[3];
  const float* msg_W = (const float*)d_in[4];
  const float* msg_b = (const float*)d_in[5];
  const float* W1 = (const float*)d_in[6];
  const float* b1 = (const float*)d_in[7];
  const float* W2 = (const float*)d_in[8];
  const float* b2 = (const float*)d_in[9];
  const float* Wp = (const float*)d_in[10];
  const float* bp = (const float*)d_in[11];

  const int N = in_sizes[0] / 128;  // 50000
  const int E = in_sizes[2];        // 1600000

  char* p = (char*)d_ws;
  auto alloc = [&](size_t bytes) {
    char* r = p;
    p += (bytes + 255) & ~(size_t)255;
    return r;
  };
  int* deg = (int*)alloc((size_t)N * 4);
  float* norm = (float*)alloc((size_t)N * 4);
  int* offs = (int*)alloc((size_t)(N + 1) * 4);
  int* cursor = (int*)alloc((size_t)N * 4);
  int* csr_srcnode = (int*)alloc((size_t)E * 4);
  int* csr_eid = (int*)alloc((size_t)E * 4);
  int* pos2node = (int*)alloc((size_t)E * 4);
  unsigned short* WfT_hi = (unsigned short*)alloc(2 * 8192 * 2);   // Z: msg_W top, KC=2
  unsigned short* WfT_lo = (unsigned short*)alloc(2 * 8192 * 2);
  unsigned short* WfB_hi = (unsigned short*)alloc(1 * 8192 * 2);   // edge: msg_W bot, KC=1
  unsigned short* WfB_lo = (unsigned short*)alloc(1 * 8192 * 2);
  unsigned short* Wf1_hi = (unsigned short*)alloc(3 * 4 * 8192 * 2);  // W1: 3 slices KC=4
  unsigned short* Wf1_lo = (unsigned short*)alloc(3 * 4 * 8192 * 2);
  unsigned short* Wf2_hi = (unsigned short*)alloc(3 * 2 * 8192 * 2);  // W2: 3 slices KC=2
  unsigned short* Wf2_lo = (unsigned short*)alloc(3 * 2 * 8192 * 2);
  float* Z = (float*)alloc((size_t)N * 128 * 4);   // Z, later reused as YA
  float* hn = (float*)alloc((size_t)N * 128 * 4);  // h_neigh
  float* C1 = (float*)alloc((size_t)N * 256 * 4);  // [YB~|YC~] L1, later H
  float* C2 = (float*)alloc((size_t)N * 256 * 4);  // [YB~|YC~] L2, later H2
  float* T1 = (float*)alloc((size_t)N * 128 * 4);
  float* T2 = (float*)alloc((size_t)N * 128 * 4);
  float* hg = (float*)alloc(128 * 4);

  hipMemsetAsync(deg, 0, (size_t)N * 4, stream);
  hipMemsetAsync(hn, 0, (size_t)N * 128 * 4, stream);
  hipMemsetAsync(hg, 0, 128 * 4, stream);

  // graph structure
  k_deg<<<2048, 256, 0, stream>>>(dst, deg, E);
  k_scan<<<1, 1024, 0, stream>>>(deg, norm, offs, cursor, N);
  k_csr<<<2048, 256, 0, stream>>>(src, dst, cursor, csr_srcnode, csr_eid, pos2node, E);

  // weight prep (fragment-ordered hi/lo bf16)
  k_prepW<<<64, 256, 0, stream>>>(msg_W, WfT_hi, WfT_lo, 2);
  k_prepW<<<32, 256, 0, stream>>>(msg_W + 128 * 128, WfB_hi, WfB_lo, 1);
  for (int s = 0; s < 3; ++s) {
    k_prepW<<<128, 256, 0, stream>>>(W1 + (size_t)s * 256 * 128,
                                     Wf1_hi + (size_t)s * 4 * 8192,
                                     Wf1_lo + (size_t)s * 4 * 8192, 4);
    k_prepW<<<64, 256, 0, stream>>>(W2 + (size_t)s * 128 * 128,
                                    Wf2_hi + (size_t)s * 2 * 8192,
                                    Wf2_lo + (size_t)s * 2 * 8192, 2);
  }

  const int MB = (N + 63) / 64;  // 782

  // Z = node_fea @ W_top + msg_b
  k_mm<<<dim3(MB, 1), 256, 0, stream>>>(node_fea, node_fea, 2, WfT_hi, WfT_lo,
                                        msg_b, nullptr, Z, nullptr, N, 2);
  // edge messages -> hn
  k_edge<<<E / 64, 256, 0, stream>>>(edge_fea, csr_srcnode, csr_eid, pos2node,
                                     WfB_hi, WfB_lo, Z, hn);

  // ----- layer 1: A = [node_fea | hn], K=256 -----
  k_mm<<<dim3(MB, 3), 256, 0, stream>>>(node_fea, hn, 2, Wf1_hi, Wf1_lo, nullptr,
                                        norm, Z /*YA*/, C1, N, 4);
  k_prop2<<<N / 4, 256, 0, stream>>>(C1, offs, csr_srcnode, norm, T1, T2, N);
  k_propc<<<N / 4, 256, 0, stream>>>(T2, Z /*YA*/, T1, b1, offs, csr_srcnode, norm,
                                     C1 /*H*/, N);

  // ----- layer 2: A = H (=C1), K=128 -----
  k_mm<<<dim3(MB, 3), 256, 0, stream>>>(C1, C1, 2, Wf2_hi, Wf2_lo, nullptr, norm,
                                        Z /*YA*/, C2, N, 2);
  k_prop2<<<N / 4, 256, 0, stream>>>(C2, offs, csr_srcnode, norm, T1, T2, N);
  k_propc<<<N / 4, 256, 0, stream>>>(T2, Z /*YA*/, T1, b2, offs, csr_srcnode, norm,
                                     C2 /*H2*/, N);

  // readout
  k_colsum<<<256, 128, 0, stream>>>(C2, hg, N);
  k_final<<<1, 128, 0, stream>>>(hg, Wp, bp, (float*)d_out, 1.0f / (float)N);
}

// Round 4
// 1617.286 us; speedup vs baseline: 4.2995x; 1.1528x over previous
//
#include <hip/hip_runtime.h>
#include <hip/hip_bf16.h>

// ---------------------------------------------------------------------------
// graphNN round 4:
//  - k_edge: 128-edge tiles, 8 waves; Z[src] register-prefetched at entry
//    (latency hidden under staging+MFMA); 4-way parallel segment walk
//  - k_mm3: 3 W-slices per layer fused in one kernel (A staged once)
//  - rest unchanged from R3 (verified correct)
// ---------------------------------------------------------------------------

typedef __attribute__((ext_vector_type(8))) short short8;
typedef __attribute__((ext_vector_type(4))) float f32x4;

static __device__ __forceinline__ unsigned short f2bf(float x) {
  union { float f; unsigned u; } v{x};
  unsigned r = v.u + 0x7FFF + ((v.u >> 16) & 1);
  return (unsigned short)(r >> 16);
}
static __device__ __forceinline__ float bf2f(unsigned short h) {
  union { unsigned u; float f; } v{(unsigned)h << 16};
  return v.f;
}

// ---------- degree histogram ----------
__global__ void k_deg(const int* __restrict__ dst, int* __restrict__ deg, int E) {
  int i = blockIdx.x * blockDim.x + threadIdx.x;
  int stride = gridDim.x * blockDim.x;
  for (; i < E; i += stride) atomicAdd(&deg[dst[i]], 1);
}

// ---------- exclusive scan over deg -> offsets, cursor; also norm ----------
__global__ void k_scan(const int* __restrict__ deg, float* __restrict__ norm,
                       int* __restrict__ offs, int* __restrict__ cursor, int N) {
  __shared__ int part[1024];
  const int t = threadIdx.x;
  const int C = (N + 1023) >> 10;
  const int b = t * C, e = min(b + C, N);
  int s = 0;
  for (int i = b; i < e; ++i) s += deg[i];
  part[t] = s;
  __syncthreads();
  for (int ofs = 1; ofs < 1024; ofs <<= 1) {
    int v = (t >= ofs) ? part[t - ofs] : 0;
    __syncthreads();
    part[t] += v;
    __syncthreads();
  }
  int base = (t == 0) ? 0 : part[t - 1];
  for (int i = b; i < e; ++i) {
    offs[i] = base;
    cursor[i] = base;
    int d = deg[i];
    base += d;
    norm[i] = rsqrtf((float)max(d, 1));
  }
  if (t == 0) offs[N] = part[1023];
}

// ---------- CSR fill: srcnode, eid, pos->dstnode ----------
__global__ void k_csr(const int* __restrict__ src, const int* __restrict__ dst,
                      int* __restrict__ cursor, int* __restrict__ csr_srcnode,
                      int* __restrict__ csr_eid, int* __restrict__ pos2node, int E) {
  int i = blockIdx.x * blockDim.x + threadIdx.x;
  int stride = gridDim.x * blockDim.x;
  for (; i < E; i += stride) {
    int d = dst[i];
    int pos = atomicAdd(&cursor[d], 1);
    csr_srcnode[pos] = src[i];
    csr_eid[pos] = i;
    pos2node[pos] = d;
  }
}

// ---------- prep: W [K][128] fp32 -> hi/lo bf16 in MFMA fragment order ------
__global__ void k_prepW(const float* __restrict__ W, unsigned short* __restrict__ Wf_hi,
                        unsigned short* __restrict__ Wf_lo, int KC) {
  int id = blockIdx.x * 256 + threadIdx.x;
  if (id >= KC * 8192) return;
  int j = id & 7;
  int l = (id >> 3) & 63;
  int rest = id >> 9;
  int ks = rest & 1, nt = (rest >> 1) & 7, kc = rest >> 4;
  int k = kc * 64 + ks * 32 + (l >> 4) * 8 + j;
  int col = nt * 16 + (l & 15);
  float w = W[(size_t)k * 128 + col];
  unsigned short hi = f2bf(w);
  unsigned short lo = f2bf(w - bf2f(hi));
  Wf_hi[id] = hi;
  Wf_lo[id] = lo;
}

// ---------- single-slice MFMA GEMM (used for Z = nf@W_top + b) --------------
__global__ __launch_bounds__(256) void k_mm(
    const float* __restrict__ A0, const unsigned short* __restrict__ Wf_hi,
    const unsigned short* __restrict__ Wf_lo, const float* __restrict__ bias,
    float* __restrict__ outA, int M, int KC) {
  __shared__ __align__(16) char lds[49152];
  unsigned short* Xhi = (unsigned short*)lds;
  unsigned short* Xlo = (unsigned short*)(lds + 8192);
  unsigned short* Whi = (unsigned short*)(lds + 16384);
  unsigned short* Wlo = (unsigned short*)(lds + 32768);

  const int t = threadIdx.x;
  const int m0 = blockIdx.x * 64;
  const int l = t & 63, mt = t >> 6;
  const int sr = t & 63, sq = t >> 6;
  const int row = min(m0 + sr, M - 1);

  f32x4 acc[8];
#pragma unroll
  for (int nt = 0; nt < 8; ++nt) acc[nt] = (f32x4){0.f, 0.f, 0.f, 0.f};

  for (int kc = 0; kc < KC; ++kc) {
    __syncthreads();
    {
      const ulong2* gh = (const ulong2*)(Wf_hi + (size_t)kc * 8192);
      const ulong2* gl = (const ulong2*)(Wf_lo + (size_t)kc * 8192);
#pragma unroll
      for (int i = 0; i < 4; ++i) {
        ((ulong2*)Whi)[i * 256 + t] = gh[i * 256 + t];
        ((ulong2*)Wlo)[i * 256 + t] = gl[i * 256 + t];
      }
    }
    {
      const float* base = A0 + (size_t)row * 128 + kc * 64;
#pragma unroll
      for (int i2 = 0; i2 < 2; ++i2) {
        const int o = sq * 2 + i2;
        float4 a4 = *(const float4*)(base + sq * 16 + i2 * 8);
        float4 b4 = *(const float4*)(base + sq * 16 + i2 * 8 + 4);
        float tmp[8] = {a4.x, a4.y, a4.z, a4.w, b4.x, b4.y, b4.z, b4.w};
        short8 vh, vl;
#pragma unroll
        for (int j = 0; j < 8; ++j) {
          unsigned short h = f2bf(tmp[j]);
          vh[j] = (short)h;
          vl[j] = (short)f2bf(tmp[j] - bf2f(h));
        }
        const int slot = (sr >> 4) * 128 + o * 16 + (sr & 15);
        *(short8*)(Xhi + (size_t)slot * 8) = vh;
        *(short8*)(Xlo + (size_t)slot * 8) = vl;
      }
    }
    __syncthreads();
    const short8* Xh8 = (const short8*)Xhi;
    const short8* Xl8 = (const short8*)Xlo;
    const short8* Wh8 = (const short8*)Whi;
    const short8* Wl8 = (const short8*)Wlo;
#pragma unroll
    for (int ks = 0; ks < 2; ++ks) {
      short8 ah = Xh8[mt * 128 + ks * 64 + l];
      short8 al = Xl8[mt * 128 + ks * 64 + l];
#pragma unroll
      for (int nt = 0; nt < 8; ++nt) {
        short8 bh = Wh8[(nt * 2 + ks) * 64 + l];
        short8 bl = Wl8[(nt * 2 + ks) * 64 + l];
        acc[nt] = __builtin_amdgcn_mfma_f32_16x16x32_bf16(ah, bh, acc[nt], 0, 0, 0);
        acc[nt] = __builtin_amdgcn_mfma_f32_16x16x32_bf16(al, bh, acc[nt], 0, 0, 0);
        acc[nt] = __builtin_amdgcn_mfma_f32_16x16x32_bf16(ah, bl, acc[nt], 0, 0, 0);
      }
    }
  }
  const int l15 = l & 15, lh = l >> 4;
#pragma unroll
  for (int nt = 0; nt < 8; ++nt) {
    const int col = nt * 16 + l15;
#pragma unroll
    for (int rg = 0; rg < 4; ++rg) {
      const int r = m0 + mt * 16 + lh * 4 + rg;
      if (r < M) outA[(size_t)r * 128 + col] = acc[nt][rg] + bias[col];
    }
  }
}

// ---------- fused 3-slice MFMA GEMM: YA, [YB~|YC~] -------------------------
// A staged once per K-chunk; W slices cycled through LDS.
__global__ __launch_bounds__(256) void k_mm3(
    const float* __restrict__ A0, const float* __restrict__ A1, int split64,
    const unsigned short* __restrict__ Wf_hi, const unsigned short* __restrict__ Wf_lo,
    const float* __restrict__ rowscale, float* __restrict__ outA,
    float* __restrict__ outBC, int M, int KC) {
  __shared__ __align__(16) char lds[49152];
  unsigned short* Xhi = (unsigned short*)lds;
  unsigned short* Xlo = (unsigned short*)(lds + 8192);
  unsigned short* Whi = (unsigned short*)(lds + 16384);
  unsigned short* Wlo = (unsigned short*)(lds + 32768);

  const int t = threadIdx.x;
  const int m0 = blockIdx.x * 64;
  const int l = t & 63, mt = t >> 6;
  const int sr = t & 63, sq = t >> 6;
  const int row = min(m0 + sr, M - 1);

  f32x4 acc[3][8];
#pragma unroll
  for (int s = 0; s < 3; ++s)
#pragma unroll
    for (int nt = 0; nt < 8; ++nt) acc[s][nt] = (f32x4){0.f, 0.f, 0.f, 0.f};

  for (int kc = 0; kc < KC; ++kc) {
    __syncthreads();
    {  // stage A chunk hi/lo (once per kc)
      const float* base = (kc < split64) ? (A0 + (size_t)row * 128 + kc * 64)
                                         : (A1 + (size_t)row * 128 + (kc - split64) * 64);
#pragma unroll
      for (int i2 = 0; i2 < 2; ++i2) {
        const int o = sq * 2 + i2;
        float4 a4 = *(const float4*)(base + sq * 16 + i2 * 8);
        float4 b4 = *(const float4*)(base + sq * 16 + i2 * 8 + 4);
        float tmp[8] = {a4.x, a4.y, a4.z, a4.w, b4.x, b4.y, b4.z, b4.w};
        short8 vh, vl;
#pragma unroll
        for (int j = 0; j < 8; ++j) {
          unsigned short h = f2bf(tmp[j]);
          vh[j] = (short)h;
          vl[j] = (short)f2bf(tmp[j] - bf2f(h));
        }
        const int slot = (sr >> 4) * 128 + o * 16 + (sr & 15);
        *(short8*)(Xhi + (size_t)slot * 8) = vh;
        *(short8*)(Xlo + (size_t)slot * 8) = vl;
      }
    }
#pragma unroll
    for (int s = 0; s < 3; ++s) {
      if (s) __syncthreads();  // prev MFMA done before W overwrite
      {
        const ulong2* gh = (const ulong2*)(Wf_hi + ((size_t)s * KC + kc) * 8192);
        const ulong2* gl = (const ulong2*)(Wf_lo + ((size_t)s * KC + kc) * 8192);
#pragma unroll
        for (int i = 0; i < 4; ++i) {
          ((ulong2*)Whi)[i * 256 + t] = gh[i * 256 + t];
          ((ulong2*)Wlo)[i * 256 + t] = gl[i * 256 + t];
        }
      }
      __syncthreads();
      const short8* Xh8 = (const short8*)Xhi;
      const short8* Xl8 = (const short8*)Xlo;
      const short8* Wh8 = (const short8*)Whi;
      const short8* Wl8 = (const short8*)Wlo;
#pragma unroll
      for (int ks = 0; ks < 2; ++ks) {
        short8 ah = Xh8[mt * 128 + ks * 64 + l];
        short8 al = Xl8[mt * 128 + ks * 64 + l];
#pragma unroll
        for (int nt = 0; nt < 8; ++nt) {
          short8 bh = Wh8[(nt * 2 + ks) * 64 + l];
          short8 bl = Wl8[(nt * 2 + ks) * 64 + l];
          acc[s][nt] = __builtin_amdgcn_mfma_f32_16x16x32_bf16(ah, bh, acc[s][nt], 0, 0, 0);
          acc[s][nt] = __builtin_amdgcn_mfma_f32_16x16x32_bf16(al, bh, acc[s][nt], 0, 0, 0);
          acc[s][nt] = __builtin_amdgcn_mfma_f32_16x16x32_bf16(ah, bl, acc[s][nt], 0, 0, 0);
        }
      }
    }
  }
  const int l15 = l & 15, lh = l >> 4;
#pragma unroll
  for (int rg = 0; rg < 4; ++rg) {
    const int r = m0 + mt * 16 + lh * 4 + rg;
    if (r < M) {
      const float rs = rowscale[r];
#pragma unroll
      for (int nt = 0; nt < 8; ++nt) {
        const int col = nt * 16 + l15;
        outA[(size_t)r * 128 + col] = acc[0][nt][rg];
        outBC[(size_t)r * 256 + col] = acc[1][nt][rg] * rs;
        outBC[(size_t)r * 256 + 128 + col] = acc[2][nt][rg] * rs;
      }
    }
  }
}

// ---------- edge GEMM (K=64) + reg-prefetched Z[src] + parallel walk --------
// 128 edges/block, 512 threads (8 waves). LDS 64KB exactly.
__global__ __launch_bounds__(512) void k_edge(
    const float* __restrict__ ef, const int* __restrict__ csr_srcnode,
    const int* __restrict__ csr_eid, const int* __restrict__ pos2node,
    const unsigned short* __restrict__ WBf_hi, const unsigned short* __restrict__ WBf_lo,
    const float* __restrict__ Z, float* __restrict__ h_neigh) {
  __shared__ __align__(16) char lds[65536];
  unsigned short* Xhi = (unsigned short*)lds;            // 16KB (1024 slots)
  unsigned short* Xlo = (unsigned short*)(lds + 16384);  // 16KB
  unsigned short* Whi = (unsigned short*)(lds + 32768);  // 16KB
  unsigned short* Wlo = (unsigned short*)(lds + 49152);  // 16KB
  float* Cs = (float*)lds;  // epilogue overlay: [128][128] f32 = 64KB

  const int t = threadIdx.x;
  const int b0 = blockIdx.x * 128;
  const int l = t & 63, mt = t >> 6;  // 8 waves, wave = 16-row M-tile

  // ---- Z prefetch: issue all loads first, consumed only in epilogue ----
  const int col = t & 127, q = t >> 7;  // quarter q: rows q*32..q*32+31
  const int rbase = b0 + q * 32;
  float z[32];
#pragma unroll
  for (int i = 0; i < 32; ++i)
    z[i] = Z[(size_t)csr_srcnode[rbase + i] * 128 + col];

  // ---- stage W_bot (2x16KB, linear copy) ----
  {
    const ulong2* gh = (const ulong2*)WBf_hi;
    const ulong2* gl = (const ulong2*)WBf_lo;
#pragma unroll
    for (int i = 0; i < 2; ++i) {
      ((ulong2*)Whi)[i * 512 + t] = gh[i * 512 + t];
      ((ulong2*)Wlo)[i * 512 + t] = gl[i * 512 + t];
    }
  }
  // ---- stage ef rows: 4 threads/row, 16 floats each ----
  {
    const int row = t >> 2;
    const int part = t & 3;
    const int eid = csr_eid[b0 + row];
    const float* rowp = ef + (size_t)eid * 64 + part * 16;
#pragma unroll
    for (int i2 = 0; i2 < 2; ++i2) {
      const int o = part * 2 + i2;
      float4 a4 = *(const float4*)(rowp + i2 * 8);
      float4 b4 = *(const float4*)(rowp + i2 * 8 + 4);
      float tmp[8] = {a4.x, a4.y, a4.z, a4.w, b4.x, b4.y, b4.z, b4.w};
      short8 vh, vl;
#pragma unroll
      for (int j = 0; j < 8; ++j) {
        unsigned short h = f2bf(tmp[j]);
        vh[j] = (short)h;
        vl[j] = (short)f2bf(tmp[j] - bf2f(h));
      }
      const int slot = (row >> 4) * 128 + o * 16 + (row & 15);
      *(short8*)(Xhi + (size_t)slot * 8) = vh;
      *(short8*)(Xlo + (size_t)slot * 8) = vl;
    }
  }
  __syncthreads();

  f32x4 acc[8];
#pragma unroll
  for (int nt = 0; nt < 8; ++nt) acc[nt] = (f32x4){0.f, 0.f, 0.f, 0.f};
  {
    const short8* Xh8 = (const short8*)Xhi;
    const short8* Xl8 = (const short8*)Xlo;
    const short8* Wh8 = (const short8*)Whi;
    const short8* Wl8 = (const short8*)Wlo;
#pragma unroll
    for (int ks = 0; ks < 2; ++ks) {
      short8 ah = Xh8[mt * 128 + ks * 64 + l];
      short8 al = Xl8[mt * 128 + ks * 64 + l];
#pragma unroll
      for (int nt = 0; nt < 8; ++nt) {
        short8 bh = Wh8[(nt * 2 + ks) * 64 + l];
        short8 bl = Wl8[(nt * 2 + ks) * 64 + l];
        acc[nt] = __builtin_amdgcn_mfma_f32_16x16x32_bf16(ah, bh, acc[nt], 0, 0, 0);
        acc[nt] = __builtin_amdgcn_mfma_f32_16x16x32_bf16(al, bh, acc[nt], 0, 0, 0);
        acc[nt] = __builtin_amdgcn_mfma_f32_16x16x32_bf16(ah, bl, acc[nt], 0, 0, 0);
      }
    }
  }
  __syncthreads();
  // ---- write C tile to LDS, XOR-swizzled ----
  const int l15 = l & 15, lh = l >> 4;
#pragma unroll
  for (int nt = 0; nt < 8; ++nt) {
#pragma unroll
    for (int rg = 0; rg < 4; ++rg) {
      const int row = mt * 16 + lh * 4 + rg;
      const int c = nt * 16 + l15;
      Cs[row * 128 + (c ^ ((row & 7) << 4))] = acc[nt][rg];
    }
  }
  __syncthreads();
  // ---- 4-way parallel segment walk (all Z already in registers) ----
  {
    int node = pos2node[rbase];
    float ssum = fmaxf(Cs[(q * 32) * 128 + (col ^ (((q * 32) & 7) << 4))] + z[0], 0.f);
#pragma unroll
    for (int r = 1; r < 32; ++r) {
      const int rr = q * 32 + r;
      float v = fmaxf(Cs[rr * 128 + (col ^ ((rr & 7) << 4))] + z[r], 0.f);
      int n2 = pos2node[b0 + rr];
      if (n2 == node) {
        ssum += v;
      } else {
        unsafeAtomicAdd(&h_neigh[(size_t)node * 128 + col], ssum);
        node = n2;
        ssum = v;
      }
    }
    unsafeAtomicAdd(&h_neigh[(size_t)node * 128 + col], ssum);
  }
}

// ---------- dual prop ----------
__global__ __launch_bounds__(256) void k_prop2(
    const float* __restrict__ comb, const int* __restrict__ offs,
    const int* __restrict__ csr_src, const float* __restrict__ norm,
    float* __restrict__ T1, float* __restrict__ T2, int N) {
  const int v = blockIdx.x * 4 + (threadIdx.x >> 6);
  const int lane = threadIdx.x & 63;
  if (v >= N) return;
  const int b = offs[v], e = offs[v + 1];
  const float4* c4 = (const float4*)comb;
  float4 a = make_float4(0.f, 0.f, 0.f, 0.f);
  for (int i = b; i < e; ++i) {
    int s = csr_src[i];
    float4 x = c4[(size_t)s * 64 + lane];
    a.x += x.x;
    a.y += x.y;
    a.z += x.z;
    a.w += x.w;
  }
  float n = norm[v];
  float sc = (lane < 32) ? n : n * n;
  a.x *= sc;
  a.y *= sc;
  a.z *= sc;
  a.w *= sc;
  float* outp = (lane < 32) ? (T1 + (size_t)v * 128 + lane * 4)
                            : (T2 + (size_t)v * 128 + (lane - 32) * 4);
  *(float4*)outp = a;
}

// ---------- prop + combine ----------
__global__ __launch_bounds__(256) void k_propc(
    const float* __restrict__ T2s, const float* __restrict__ YA,
    const float* __restrict__ T1, const float* __restrict__ bias,
    const int* __restrict__ offs, const int* __restrict__ csr_src,
    const float* __restrict__ norm, float* __restrict__ H, int N) {
  const int v = blockIdx.x * 4 + (threadIdx.x >> 6);
  const int lane = threadIdx.x & 63;
  if (v >= N) return;
  const int b = offs[v], e = offs[v + 1];
  const float2* t2 = (const float2*)T2s;
  float ax = 0.f, ay = 0.f;
  for (int i = b; i < e; ++i) {
    int s = csr_src[i];
    float2 x = t2[(size_t)s * 64 + lane];
    ax += x.x;
    ay += x.y;
  }
  float n = norm[v];
  float2 ya = ((const float2*)YA)[(size_t)v * 64 + lane];
  float2 t1 = ((const float2*)T1)[(size_t)v * 64 + lane];
  float2 bb = ((const float2*)bias)[lane];
  float hx = ya.x + t1.x + n * ax + bb.x;
  float hy = ya.y + t1.y + n * ay + bb.y;
  hx = hx > 0.f ? hx : 0.f;
  hy = hy > 0.f ? hy : 0.f;
  ((float2*)H)[(size_t)v * 64 + lane] = make_float2(hx, hy);
}

// ---------- column sums ----------
__global__ void k_colsum(const float* __restrict__ h, float* __restrict__ hg, int N) {
  const int t = threadIdx.x;
  const int per = (N + gridDim.x - 1) / gridDim.x;
  const int n0 = blockIdx.x * per, n1 = min(n0 + per, N);
  float s = 0.f;
  for (int n = n0; n < n1; ++n) s += h[(size_t)n * 128 + t];
  unsafeAtomicAdd(&hg[t], s);
}

// ---------- final ----------
__global__ void k_final(const float* __restrict__ hg, const float* __restrict__ Wp,
                        const float* __restrict__ bp, float* __restrict__ out,
                        float invN) {
  __shared__ float red[128];
  const int t = threadIdx.x;
  red[t] = hg[t] * invN * Wp[t];
  __syncthreads();
  for (int s = 64; s > 0; s >>= 1) {
    if (t < s) red[t] += red[t + s];
    __syncthreads();
  }
  if (t == 0) out[0] = red[0] + bp[0];
}

extern "C" void kernel_launch(void* const* d_in, const int* in_sizes, int n_in,
                              void* d_out, int out_size, void* d_ws, size_t ws_size,
                              hipStream_t stream) {
  const float* node_fea = (const float*)d_in[0];
  const float* edge_fea = (const float*)d_in[1];
  const int* src = (const int*)d_in[2];
  const int* dst = (const int*)d_in[3];
  const float* msg_W = (const float*)d_in[4];
  const float* msg_b = (const float*)d_in[5];
  const float* W1 = (const float*)d_in[6];
  const float* b1 = (const float*)d_in[7];
  const float* W2 = (const float*)d_in[8];
  const float* b2 = (const float*)d_in[9];
  const float* Wp = (const float*)d_in[10];
  const float* bp = (const float*)d_in[11];

  const int N = in_sizes[0] / 128;  // 50000
  const int E = in_sizes[2];        // 1600000

  char* p = (char*)d_ws;
  auto alloc = [&](size_t bytes) {
    char* r = p;
    p += (bytes + 255) & ~(size_t)255;
    return r;
  };
  int* deg = (int*)alloc((size_t)N * 4);
  float* norm = (float*)alloc((size_t)N * 4);
  int* offs = (int*)alloc((size_t)(N + 1) * 4);
  int* cursor = (int*)alloc((size_t)N * 4);
  int* csr_srcnode = (int*)alloc((size_t)E * 4);
  int* csr_eid = (int*)alloc((size_t)E * 4);
  int* pos2node = (int*)alloc((size_t)E * 4);
  unsigned short* WfT_hi = (unsigned short*)alloc(2 * 8192 * 2);
  unsigned short* WfT_lo = (unsigned short*)alloc(2 * 8192 * 2);
  unsigned short* WfB_hi = (unsigned short*)alloc(1 * 8192 * 2);
  unsigned short* WfB_lo = (unsigned short*)alloc(1 * 8192 * 2);
  unsigned short* Wf1_hi = (unsigned short*)alloc(3 * 4 * 8192 * 2);
  unsigned short* Wf1_lo = (unsigned short*)alloc(3 * 4 * 8192 * 2);
  unsigned short* Wf2_hi = (unsigned short*)alloc(3 * 2 * 8192 * 2);
  unsigned short* Wf2_lo = (unsigned short*)alloc(3 * 2 * 8192 * 2);
  float* Z = (float*)alloc((size_t)N * 128 * 4);   // Z, later reused as YA
  float* hn = (float*)alloc((size_t)N * 128 * 4);  // h_neigh
  float* C1 = (float*)alloc((size_t)N * 256 * 4);  // [YB~|YC~] L1, later H
  float* C2 = (float*)alloc((size_t)N * 256 * 4);  // [YB~|YC~] L2, later H2
  float* T1 = (float*)alloc((size_t)N * 128 * 4);
  float* T2 = (float*)alloc((size_t)N * 128 * 4);
  float* hg = (float*)alloc(128 * 4);

  hipMemsetAsync(deg, 0, (size_t)N * 4, stream);
  hipMemsetAsync(hn, 0, (size_t)N * 128 * 4, stream);
  hipMemsetAsync(hg, 0, 128 * 4, stream);

  // graph structure
  k_deg<<<2048, 256, 0, stream>>>(dst, deg, E);
  k_scan<<<1, 1024, 0, stream>>>(deg, norm, offs, cursor, N);
  k_csr<<<2048, 256, 0, stream>>>(src, dst, cursor, csr_srcnode, csr_eid, pos2node, E);

  // weight prep
  k_prepW<<<64, 256, 0, stream>>>(msg_W, WfT_hi, WfT_lo, 2);
  k_prepW<<<32, 256, 0, stream>>>(msg_W + 128 * 128, WfB_hi, WfB_lo, 1);
  for (int s = 0; s < 3; ++s) {
    k_prepW<<<128, 256, 0, stream>>>(W1 + (size_t)s * 256 * 128,
                                     Wf1_hi + (size_t)s * 4 * 8192,
                                     Wf1_lo + (size_t)s * 4 * 8192, 4);
    k_prepW<<<64, 256, 0, stream>>>(W2 + (size_t)s * 128 * 128,
                                    Wf2_hi + (size_t)s * 2 * 8192,
                                    Wf2_lo + (size_t)s * 2 * 8192, 2);
  }

  const int MB = (N + 63) / 64;  // 782

  // Z = node_fea @ W_top + msg_b
  k_mm<<<MB, 256, 0, stream>>>(node_fea, WfT_hi, WfT_lo, msg_b, Z, N, 2);
  // edge messages -> hn
  k_edge<<<E / 128, 512, 0, stream>>>(edge_fea, csr_srcnode, csr_eid, pos2node,
                                      WfB_hi, WfB_lo, Z, hn);

  // ----- layer 1: A = [node_fea | hn], K=256 -----
  k_mm3<<<MB, 256, 0, stream>>>(node_fea, hn, 2, Wf1_hi, Wf1_lo, norm, Z /*YA*/,
                                C1, N, 4);
  k_prop2<<<(N + 3) / 4, 256, 0, stream>>>(C1, offs, csr_srcnode, norm, T1, T2, N);
  k_propc<<<(N + 3) / 4, 256, 0, stream>>>(T2, Z, T1, b1, offs, csr_srcnode, norm,
                                           C1 /*H*/, N);

  // ----- layer 2: A = H (=C1), K=128 -----
  k_mm3<<<MB, 256, 0, stream>>>(C1, C1, 2, Wf2_hi, Wf2_lo, norm, Z /*YA*/, C2, N, 2);
  k_prop2<<<(N + 3) / 4, 256, 0, stream>>>(C2, offs, csr_srcnode, norm, T1, T2, N);
  k_propc<<<(N + 3) / 4, 256, 0, stream>>>(T2, Z, T1, b2, offs, csr_srcnode, norm,
                                           C2 /*H2*/, N);

  // readout
  k_colsum<<<256, 128, 0, stream>>>(C2, hg, N);
  k_final<<<1, 128, 0, stream>>>(hg, Wp, bp, (float*)d_out, 1.0f / (float)N);
}

// Round 6
// 1471.714 us; speedup vs baseline: 4.7248x; 1.0989x over previous
//
#include <hip/hip_runtime.h>
#include <hip/hip_bf16.h>

// ---------------------------------------------------------------------------
// graphNN round 6 (= round 5 with compile fix: WfB_hi/WfB_lo naming):
//  - bf16 activations everywhere the error budget allows (weights stay hi/lo):
//    Z bf16, ef staged bf16, C-tile bf16 in LDS, comb/T2s/H bf16
//  - k_edge: 48KB LDS -> 3 blocks/CU; bank-correct C swizzle; packed Z regs
//  - layer-2 GEMM: bf16 A staged directly (no conversion), 2 MFMA products
// ---------------------------------------------------------------------------

typedef __attribute__((ext_vector_type(8))) short short8;
typedef __attribute__((ext_vector_type(4))) float f32x4;
typedef unsigned short ushort_t;

static __device__ __forceinline__ unsigned short f2bf(float x) {
  union { float f; unsigned u; } v{x};
  unsigned r = v.u + 0x7FFF + ((v.u >> 16) & 1);
  return (unsigned short)(r >> 16);
}
static __device__ __forceinline__ float bf2f(unsigned short h) {
  union { unsigned u; float f; } v{(unsigned)h << 16};
  return v.f;
}
static __device__ __forceinline__ float u2f(unsigned u) {
  union { unsigned u; float f; } v{u};
  return v.f;
}

// ---------- degree histogram ----------
__global__ void k_deg(const int* __restrict__ dst, int* __restrict__ deg, int E) {
  int i = blockIdx.x * blockDim.x + threadIdx.x;
  int stride = gridDim.x * blockDim.x;
  for (; i < E; i += stride) atomicAdd(&deg[dst[i]], 1);
}

// ---------- exclusive scan over deg -> offsets, cursor; also norm ----------
__global__ void k_scan(const int* __restrict__ deg, float* __restrict__ norm,
                       int* __restrict__ offs, int* __restrict__ cursor, int N) {
  __shared__ int part[1024];
  const int t = threadIdx.x;
  const int C = (N + 1023) >> 10;
  const int b = t * C, e = min(b + C, N);
  int s = 0;
  for (int i = b; i < e; ++i) s += deg[i];
  part[t] = s;
  __syncthreads();
  for (int ofs = 1; ofs < 1024; ofs <<= 1) {
    int v = (t >= ofs) ? part[t - ofs] : 0;
    __syncthreads();
    part[t] += v;
    __syncthreads();
  }
  int base = (t == 0) ? 0 : part[t - 1];
  for (int i = b; i < e; ++i) {
    offs[i] = base;
    cursor[i] = base;
    int d = deg[i];
    base += d;
    norm[i] = rsqrtf((float)max(d, 1));
  }
  if (t == 0) offs[N] = part[1023];
}

// ---------- CSR fill ----------
__global__ void k_csr(const int* __restrict__ src, const int* __restrict__ dst,
                      int* __restrict__ cursor, int* __restrict__ csr_srcnode,
                      int* __restrict__ csr_eid, int* __restrict__ pos2node, int E) {
  int i = blockIdx.x * blockDim.x + threadIdx.x;
  int stride = gridDim.x * blockDim.x;
  for (; i < E; i += stride) {
    int d = dst[i];
    int pos = atomicAdd(&cursor[d], 1);
    csr_srcnode[pos] = src[i];
    csr_eid[pos] = i;
    pos2node[pos] = d;
  }
}

// ---------- prep: W [K][128] fp32 -> hi/lo bf16 in MFMA fragment order ------
__global__ void k_prepW(const float* __restrict__ W, ushort_t* __restrict__ Wf_hi,
                        ushort_t* __restrict__ Wf_lo, int KC) {
  int id = blockIdx.x * 256 + threadIdx.x;
  if (id >= KC * 8192) return;
  int j = id & 7;
  int l = (id >> 3) & 63;
  int rest = id >> 9;
  int ks = rest & 1, nt = (rest >> 1) & 7, kc = rest >> 4;
  int k = kc * 64 + ks * 32 + (l >> 4) * 8 + j;
  int col = nt * 16 + (l & 15);
  float w = W[(size_t)k * 128 + col];
  unsigned short hi = f2bf(w);
  unsigned short lo = f2bf(w - bf2f(hi));
  Wf_hi[id] = hi;
  Wf_lo[id] = lo;
}

// ---------- Z = nf @ W_top + b (fp32 hi/lo in, bf16 out) --------------------
__global__ __launch_bounds__(256) void k_mm(
    const float* __restrict__ A0, const ushort_t* __restrict__ Wf_hi,
    const ushort_t* __restrict__ Wf_lo, const float* __restrict__ bias,
    ushort_t* __restrict__ outZ, int M, int KC) {
  __shared__ __align__(16) char lds[49152];
  ushort_t* Xhi = (ushort_t*)lds;
  ushort_t* Xlo = (ushort_t*)(lds + 8192);
  ushort_t* Whi = (ushort_t*)(lds + 16384);
  ushort_t* Wlo = (ushort_t*)(lds + 32768);

  const int t = threadIdx.x;
  const int m0 = blockIdx.x * 64;
  const int l = t & 63, mt = t >> 6;
  const int sr = t & 63, sq = t >> 6;
  const int row = min(m0 + sr, M - 1);

  f32x4 acc[8];
#pragma unroll
  for (int nt = 0; nt < 8; ++nt) acc[nt] = (f32x4){0.f, 0.f, 0.f, 0.f};

  for (int kc = 0; kc < KC; ++kc) {
    __syncthreads();
    {
      const ulong2* gh = (const ulong2*)(Wf_hi + (size_t)kc * 8192);
      const ulong2* gl = (const ulong2*)(Wf_lo + (size_t)kc * 8192);
#pragma unroll
      for (int i = 0; i < 4; ++i) {
        ((ulong2*)Whi)[i * 256 + t] = gh[i * 256 + t];
        ((ulong2*)Wlo)[i * 256 + t] = gl[i * 256 + t];
      }
    }
    {
      const float* base = A0 + (size_t)row * 128 + kc * 64;
#pragma unroll
      for (int i2 = 0; i2 < 2; ++i2) {
        const int o = sq * 2 + i2;
        float4 a4 = *(const float4*)(base + sq * 16 + i2 * 8);
        float4 b4 = *(const float4*)(base + sq * 16 + i2 * 8 + 4);
        float tmp[8] = {a4.x, a4.y, a4.z, a4.w, b4.x, b4.y, b4.z, b4.w};
        short8 vh, vl;
#pragma unroll
        for (int j = 0; j < 8; ++j) {
          unsigned short h = f2bf(tmp[j]);
          vh[j] = (short)h;
          vl[j] = (short)f2bf(tmp[j] - bf2f(h));
        }
        const int slot = (sr >> 4) * 128 + o * 16 + (sr & 15);
        *(short8*)(Xhi + (size_t)slot * 8) = vh;
        *(short8*)(Xlo + (size_t)slot * 8) = vl;
      }
    }
    __syncthreads();
    const short8* Xh8 = (const short8*)Xhi;
    const short8* Xl8 = (const short8*)Xlo;
    const short8* Wh8 = (const short8*)Whi;
    const short8* Wl8 = (const short8*)Wlo;
#pragma unroll
    for (int ks = 0; ks < 2; ++ks) {
      short8 ah = Xh8[mt * 128 + ks * 64 + l];
      short8 al = Xl8[mt * 128 + ks * 64 + l];
#pragma unroll
      for (int nt = 0; nt < 8; ++nt) {
        short8 bh = Wh8[(nt * 2 + ks) * 64 + l];
        short8 bl = Wl8[(nt * 2 + ks) * 64 + l];
        acc[nt] = __builtin_amdgcn_mfma_f32_16x16x32_bf16(ah, bh, acc[nt], 0, 0, 0);
        acc[nt] = __builtin_amdgcn_mfma_f32_16x16x32_bf16(al, bh, acc[nt], 0, 0, 0);
        acc[nt] = __builtin_amdgcn_mfma_f32_16x16x32_bf16(ah, bl, acc[nt], 0, 0, 0);
      }
    }
  }
  const int l15 = l & 15, lh = l >> 4;
#pragma unroll
  for (int nt = 0; nt < 8; ++nt) {
    const int col = nt * 16 + l15;
#pragma unroll
    for (int rg = 0; rg < 4; ++rg) {
      const int r = m0 + mt * 16 + lh * 4 + rg;
      if (r < M) outZ[(size_t)r * 128 + col] = f2bf(acc[nt][rg] + bias[col]);
    }
  }
}

// ---------- fused 3-slice GEMM: YA fp32, [YB~|YC~] bf16 ---------------------
// BF16A=0: A fp32 split across A0/A1, hi/lo (3 products)
// BF16A=1: A bf16 [M][128] in A0v, staged directly (2 products)
template <int BF16A>
__global__ __launch_bounds__(256) void k_mm3(
    const void* __restrict__ A0v, const float* __restrict__ A1, int split64,
    const ushort_t* __restrict__ Wf_hi, const ushort_t* __restrict__ Wf_lo,
    const float* __restrict__ rowscale, float* __restrict__ outA,
    ushort_t* __restrict__ outBC, int M, int KC) {
  __shared__ __align__(16) char lds[49152];
  ushort_t* Xhi = (ushort_t*)lds;
  ushort_t* Xlo = (ushort_t*)(lds + 8192);
  ushort_t* Whi = (ushort_t*)(lds + 16384);
  ushort_t* Wlo = (ushort_t*)(lds + 32768);

  const int t = threadIdx.x;
  const int m0 = blockIdx.x * 64;
  const int l = t & 63, mt = t >> 6;
  const int sr = t & 63, sq = t >> 6;
  const int row = min(m0 + sr, M - 1);

  f32x4 acc[3][8];
#pragma unroll
  for (int s = 0; s < 3; ++s)
#pragma unroll
    for (int nt = 0; nt < 8; ++nt) acc[s][nt] = (f32x4){0.f, 0.f, 0.f, 0.f};

  for (int kc = 0; kc < KC; ++kc) {
    __syncthreads();
    if constexpr (BF16A) {
      const ushort_t* base = (const ushort_t*)A0v + (size_t)row * 128 + kc * 64;
#pragma unroll
      for (int i2 = 0; i2 < 2; ++i2) {
        const int o = sq * 2 + i2;
        short8 v = *(const short8*)(base + sq * 16 + i2 * 8);
        const int slot = (sr >> 4) * 128 + o * 16 + (sr & 15);
        *(short8*)(Xhi + (size_t)slot * 8) = v;
      }
    } else {
      const float* A0 = (const float*)A0v;
      const float* base = (kc < split64) ? (A0 + (size_t)row * 128 + kc * 64)
                                         : (A1 + (size_t)row * 128 + (kc - split64) * 64);
#pragma unroll
      for (int i2 = 0; i2 < 2; ++i2) {
        const int o = sq * 2 + i2;
        float4 a4 = *(const float4*)(base + sq * 16 + i2 * 8);
        float4 b4 = *(const float4*)(base + sq * 16 + i2 * 8 + 4);
        float tmp[8] = {a4.x, a4.y, a4.z, a4.w, b4.x, b4.y, b4.z, b4.w};
        short8 vh, vl;
#pragma unroll
        for (int j = 0; j < 8; ++j) {
          unsigned short h = f2bf(tmp[j]);
          vh[j] = (short)h;
          vl[j] = (short)f2bf(tmp[j] - bf2f(h));
        }
        const int slot = (sr >> 4) * 128 + o * 16 + (sr & 15);
        *(short8*)(Xhi + (size_t)slot * 8) = vh;
        *(short8*)(Xlo + (size_t)slot * 8) = vl;
      }
    }
#pragma unroll
    for (int s = 0; s < 3; ++s) {
      if (s) __syncthreads();
      {
        const ulong2* gh = (const ulong2*)(Wf_hi + ((size_t)s * KC + kc) * 8192);
        const ulong2* gl = (const ulong2*)(Wf_lo + ((size_t)s * KC + kc) * 8192);
#pragma unroll
        for (int i = 0; i < 4; ++i) {
          ((ulong2*)Whi)[i * 256 + t] = gh[i * 256 + t];
          ((ulong2*)Wlo)[i * 256 + t] = gl[i * 256 + t];
        }
      }
      __syncthreads();
      const short8* Xh8 = (const short8*)Xhi;
      const short8* Xl8 = (const short8*)Xlo;
      const short8* Wh8 = (const short8*)Whi;
      const short8* Wl8 = (const short8*)Wlo;
#pragma unroll
      for (int ks = 0; ks < 2; ++ks) {
        short8 ah = Xh8[mt * 128 + ks * 64 + l];
        short8 al;
        if constexpr (!BF16A) al = Xl8[mt * 128 + ks * 64 + l];
#pragma unroll
        for (int nt = 0; nt < 8; ++nt) {
          short8 bh = Wh8[(nt * 2 + ks) * 64 + l];
          short8 bl = Wl8[(nt * 2 + ks) * 64 + l];
          acc[s][nt] = __builtin_amdgcn_mfma_f32_16x16x32_bf16(ah, bh, acc[s][nt], 0, 0, 0);
          if constexpr (!BF16A)
            acc[s][nt] = __builtin_amdgcn_mfma_f32_16x16x32_bf16(al, bh, acc[s][nt], 0, 0, 0);
          acc[s][nt] = __builtin_amdgcn_mfma_f32_16x16x32_bf16(ah, bl, acc[s][nt], 0, 0, 0);
        }
      }
    }
  }
  const int l15 = l & 15, lh = l >> 4;
#pragma unroll
  for (int rg = 0; rg < 4; ++rg) {
    const int r = m0 + mt * 16 + lh * 4 + rg;
    if (r < M) {
      const float rs = rowscale[r];
#pragma unroll
      for (int nt = 0; nt < 8; ++nt) {
        const int col = nt * 16 + l15;
        outA[(size_t)r * 128 + col] = acc[0][nt][rg];
        outBC[(size_t)r * 256 + col] = f2bf(acc[1][nt][rg] * rs);
        outBC[(size_t)r * 256 + 128 + col] = f2bf(acc[2][nt][rg] * rs);
      }
    }
  }
}

// ---------- edge GEMM (K=64, bf16 ef) + bf16 Z + parallel walk --------------
// 128 edges/block, 512 threads. LDS 48KB -> 3 blocks/CU.
__global__ __launch_bounds__(512, 6) void k_edge(
    const float* __restrict__ ef, const int* __restrict__ csr_srcnode,
    const int* __restrict__ csr_eid, const int* __restrict__ pos2node,
    const ushort_t* __restrict__ WfB_hi, const ushort_t* __restrict__ WfB_lo,
    const ushort_t* __restrict__ Zb, float* __restrict__ h_neigh) {
  __shared__ __align__(16) char lds[49152];
  ushort_t* Xh = (ushort_t*)lds;             // [0,16K)
  ushort_t* Whi = (ushort_t*)(lds + 16384);  // [16K,32K)
  ushort_t* Wlo = (ushort_t*)(lds + 32768);  // [32K,48K)
  ushort_t* Cs = (ushort_t*)lds;             // epilogue overlay [128][128] bf16 = 32KB

  const int t = threadIdx.x;
  const int b0 = blockIdx.x * 128;
  const int l = t & 63, mt = t >> 6;
  const int col = t & 127, q = t >> 7;
  const int rbase = b0 + q * 32;

  // ---- Z prefetch (bf16, packed 2/reg), consumed only in the walk ----
  unsigned zp[16];
#pragma unroll
  for (int i = 0; i < 16; ++i) {
    unsigned a = Zb[(size_t)csr_srcnode[rbase + 2 * i] * 128 + col];
    unsigned b = Zb[(size_t)csr_srcnode[rbase + 2 * i + 1] * 128 + col];
    zp[i] = a | (b << 16);
  }
  // ---- stage W hi/lo (2 x 16KB linear) ----
  {
    const ulong2* gh = (const ulong2*)WfB_hi;
    const ulong2* gl = (const ulong2*)WfB_lo;
#pragma unroll
    for (int i = 0; i < 2; ++i) {
      ((ulong2*)Whi)[i * 512 + t] = gh[i * 512 + t];
      ((ulong2*)Wlo)[i * 512 + t] = gl[i * 512 + t];
    }
  }
  // ---- stage ef rows, bf16 hi only ----
  {
    const int row = t >> 2, part = t & 3;
    const int eid = csr_eid[b0 + row];
    const float* rowp = ef + (size_t)eid * 64 + part * 16;
#pragma unroll
    for (int i2 = 0; i2 < 2; ++i2) {
      const int o = part * 2 + i2;
      float4 a4 = *(const float4*)(rowp + i2 * 8);
      float4 b4 = *(const float4*)(rowp + i2 * 8 + 4);
      float tmp[8] = {a4.x, a4.y, a4.z, a4.w, b4.x, b4.y, b4.z, b4.w};
      short8 vh;
#pragma unroll
      for (int j = 0; j < 8; ++j) vh[j] = (short)f2bf(tmp[j]);
      const int slot = (row >> 4) * 128 + o * 16 + (row & 15);
      *(short8*)(Xh + (size_t)slot * 8) = vh;
    }
  }
  __syncthreads();

  f32x4 acc[8];
#pragma unroll
  for (int nt = 0; nt < 8; ++nt) acc[nt] = (f32x4){0.f, 0.f, 0.f, 0.f};
  {
    const short8* Xh8 = (const short8*)Xh;
    const short8* Wh8 = (const short8*)Whi;
    const short8* Wl8 = (const short8*)Wlo;
#pragma unroll
    for (int ks = 0; ks < 2; ++ks) {
      short8 ah = Xh8[mt * 128 + ks * 64 + l];
#pragma unroll
      for (int nt = 0; nt < 8; ++nt) {
        short8 bh = Wh8[(nt * 2 + ks) * 64 + l];
        short8 bl = Wl8[(nt * 2 + ks) * 64 + l];
        acc[nt] = __builtin_amdgcn_mfma_f32_16x16x32_bf16(ah, bh, acc[nt], 0, 0, 0);
        acc[nt] = __builtin_amdgcn_mfma_f32_16x16x32_bf16(ah, bl, acc[nt], 0, 0, 0);
      }
    }
  }
  __syncthreads();
  // ---- C tile -> LDS bf16, bank-correct swizzle (col ^= ((row>>2)&3)<<4) ----
  const int l15 = l & 15, lh = l >> 4;
#pragma unroll
  for (int nt = 0; nt < 8; ++nt) {
#pragma unroll
    for (int rg = 0; rg < 4; ++rg) {
      const int row = mt * 16 + lh * 4 + rg;
      const int c = nt * 16 + l15;
      Cs[row * 128 + (c ^ (((row >> 2) & 3) << 4))] = f2bf(acc[nt][rg]);
    }
  }
  __syncthreads();
  // ---- 4-way parallel segment walk ----
  {
    int node = pos2node[rbase];
    float ssum = 0.f;
#pragma unroll
    for (int r = 0; r < 32; ++r) {
      const int rr = q * 32 + r;
      float cz = bf2f(Cs[rr * 128 + (col ^ (((rr >> 2) & 3) << 4))]);
      float zf = u2f((r & 1) ? (zp[r >> 1] & 0xffff0000u) : (zp[r >> 1] << 16));
      float v = fmaxf(cz + zf, 0.f);
      if (r == 0) {
        ssum = v;
      } else {
        int n2 = pos2node[b0 + rr];
        if (n2 == node) {
          ssum += v;
        } else {
          unsafeAtomicAdd(&h_neigh[(size_t)node * 128 + col], ssum);
          node = n2;
          ssum = v;
        }
      }
    }
    unsafeAtomicAdd(&h_neigh[(size_t)node * 128 + col], ssum);
  }
}

// ---------- dual prop: comb bf16 [N][256] -> T1 fp32, T2s bf16 --------------
__global__ __launch_bounds__(256) void k_prop2(
    const ushort_t* __restrict__ comb, const int* __restrict__ offs,
    const int* __restrict__ csr_src, const float* __restrict__ norm,
    float* __restrict__ T1, ushort_t* __restrict__ T2, int N) {
  const int v = blockIdx.x * 4 + (threadIdx.x >> 6);
  const int lane = threadIdx.x & 63;
  if (v >= N) return;
  const int b = offs[v], e = offs[v + 1];
  const uint2* c2 = (const uint2*)comb;  // 4 bf16 per lane
  float a0 = 0.f, a1 = 0.f, a2 = 0.f, a3 = 0.f;
  for (int i = b; i < e; ++i) {
    int s = csr_src[i];
    uint2 x = c2[(size_t)s * 64 + lane];
    a0 += u2f(x.x << 16);
    a1 += u2f(x.x & 0xffff0000u);
    a2 += u2f(x.y << 16);
    a3 += u2f(x.y & 0xffff0000u);
  }
  float n = norm[v];
  if (lane < 32) {
    float4 o = make_float4(a0 * n, a1 * n, a2 * n, a3 * n);
    *(float4*)(T1 + (size_t)v * 128 + lane * 4) = o;
  } else {
    float s2 = n * n;
    unsigned lo = (unsigned)f2bf(a0 * s2) | ((unsigned)f2bf(a1 * s2) << 16);
    unsigned hi = (unsigned)f2bf(a2 * s2) | ((unsigned)f2bf(a3 * s2) << 16);
    uint2 o;
    o.x = lo;
    o.y = hi;
    *(uint2*)(T2 + (size_t)v * 128 + (lane - 32) * 4) = o;
  }
}

// ---------- prop + combine: H bf16 = relu(YA + T1 + n*sum T2s[src] + b) -----
__global__ __launch_bounds__(256) void k_propc(
    const ushort_t* __restrict__ T2s, const float* __restrict__ YA,
    const float* __restrict__ T1, const float* __restrict__ bias,
    const int* __restrict__ offs, const int* __restrict__ csr_src,
    const float* __restrict__ norm, ushort_t* __restrict__ H, int N) {
  const int v = blockIdx.x * 4 + (threadIdx.x >> 6);
  const int lane = threadIdx.x & 63;
  if (v >= N) return;
  const int b = offs[v], e = offs[v + 1];
  const unsigned* t2 = (const unsigned*)T2s;  // 2 bf16 per lane
  float ax = 0.f, ay = 0.f;
  for (int i = b; i < e; ++i) {
    int s = csr_src[i];
    unsigned x = t2[(size_t)s * 64 + lane];
    ax += u2f(x << 16);
    ay += u2f(x & 0xffff0000u);
  }
  float n = norm[v];
  float2 ya = ((const float2*)YA)[(size_t)v * 64 + lane];
  float2 t1 = ((const float2*)T1)[(size_t)v * 64 + lane];
  float2 bb = ((const float2*)bias)[lane];
  float hx = fmaxf(ya.x + t1.x + n * ax + bb.x, 0.f);
  float hy = fmaxf(ya.y + t1.y + n * ay + bb.y, 0.f);
  ((unsigned*)H)[(size_t)v * 64 + lane] = (unsigned)f2bf(hx) | ((unsigned)f2bf(hy) << 16);
}

// ---------- column sums of bf16 h -> hg[128] ----------
__global__ void k_colsum(const ushort_t* __restrict__ h, float* __restrict__ hg, int N) {
  const int t = threadIdx.x;  // 128
  const int per = (N + gridDim.x - 1) / gridDim.x;
  const int n0 = blockIdx.x * per, n1 = min(n0 + per, N);
  float s = 0.f;
  for (int n = n0; n < n1; ++n) s += bf2f(h[(size_t)n * 128 + t]);
  unsafeAtomicAdd(&hg[t], s);
}

// ---------- final ----------
__global__ void k_final(const float* __restrict__ hg, const float* __restrict__ Wp,
                        const float* __restrict__ bp, float* __restrict__ out,
                        float invN) {
  __shared__ float red[128];
  const int t = threadIdx.x;
  red[t] = hg[t] * invN * Wp[t];
  __syncthreads();
  for (int s = 64; s > 0; s >>= 1) {
    if (t < s) red[t] += red[t + s];
    __syncthreads();
  }
  if (t == 0) out[0] = red[0] + bp[0];
}

extern "C" void kernel_launch(void* const* d_in, const int* in_sizes, int n_in,
                              void* d_out, int out_size, void* d_ws, size_t ws_size,
                              hipStream_t stream) {
  const float* node_fea = (const float*)d_in[0];
  const float* edge_fea = (const float*)d_in[1];
  const int* src = (const int*)d_in[2];
  const int* dst = (const int*)d_in[3];
  const float* msg_W = (const float*)d_in[4];
  const float* msg_b = (const float*)d_in[5];
  const float* W1 = (const float*)d_in[6];
  const float* b1 = (const float*)d_in[7];
  const float* W2 = (const float*)d_in[8];
  const float* b2 = (const float*)d_in[9];
  const float* Wp = (const float*)d_in[10];
  const float* bp = (const float*)d_in[11];

  const int N = in_sizes[0] / 128;  // 50000
  const int E = in_sizes[2];        // 1600000

  char* p = (char*)d_ws;
  auto alloc = [&](size_t bytes) {
    char* r = p;
    p += (bytes + 255) & ~(size_t)255;
    return r;
  };
  int* deg = (int*)alloc((size_t)N * 4);
  float* norm = (float*)alloc((size_t)N * 4);
  int* offs = (int*)alloc((size_t)(N + 1) * 4);
  int* cursor = (int*)alloc((size_t)N * 4);
  int* csr_srcnode = (int*)alloc((size_t)E * 4);
  int* csr_eid = (int*)alloc((size_t)E * 4);
  int* pos2node = (int*)alloc((size_t)E * 4);
  ushort_t* WfT_hi = (ushort_t*)alloc(2 * 8192 * 2);
  ushort_t* WfT_lo = (ushort_t*)alloc(2 * 8192 * 2);
  ushort_t* WfB_hi = (ushort_t*)alloc(1 * 8192 * 2);
  ushort_t* WfB_lo = (ushort_t*)alloc(1 * 8192 * 2);
  ushort_t* Wf1_hi = (ushort_t*)alloc(3 * 4 * 8192 * 2);
  ushort_t* Wf1_lo = (ushort_t*)alloc(3 * 4 * 8192 * 2);
  ushort_t* Wf2_hi = (ushort_t*)alloc(3 * 2 * 8192 * 2);
  ushort_t* Wf2_lo = (ushort_t*)alloc(3 * 2 * 8192 * 2);
  ushort_t* Zb = (ushort_t*)alloc((size_t)N * 128 * 2);  // bf16 Z
  float* YA = (float*)alloc((size_t)N * 128 * 4);
  float* hn = (float*)alloc((size_t)N * 128 * 4);        // fp32 (atomic target)
  ushort_t* C1 = (ushort_t*)alloc((size_t)N * 256 * 2);  // comb L1 / H (bf16)
  ushort_t* C2 = (ushort_t*)alloc((size_t)N * 256 * 2);  // comb L2 / H2 (bf16)
  float* T1 = (float*)alloc((size_t)N * 128 * 4);
  ushort_t* T2 = (ushort_t*)alloc((size_t)N * 128 * 2);  // bf16 (gathered)
  float* hg = (float*)alloc(128 * 4);

  hipMemsetAsync(deg, 0, (size_t)N * 4, stream);
  hipMemsetAsync(hn, 0, (size_t)N * 128 * 4, stream);
  hipMemsetAsync(hg, 0, 128 * 4, stream);

  // graph structure
  k_deg<<<2048, 256, 0, stream>>>(dst, deg, E);
  k_scan<<<1, 1024, 0, stream>>>(deg, norm, offs, cursor, N);
  k_csr<<<2048, 256, 0, stream>>>(src, dst, cursor, csr_srcnode, csr_eid, pos2node, E);

  // weight prep
  k_prepW<<<64, 256, 0, stream>>>(msg_W, WfT_hi, WfT_lo, 2);
  k_prepW<<<32, 256, 0, stream>>>(msg_W + 128 * 128, WfB_hi, WfB_lo, 1);
  for (int s = 0; s < 3; ++s) {
    k_prepW<<<128, 256, 0, stream>>>(W1 + (size_t)s * 256 * 128,
                                     Wf1_hi + (size_t)s * 4 * 8192,
                                     Wf1_lo + (size_t)s * 4 * 8192, 4);
    k_prepW<<<64, 256, 0, stream>>>(W2 + (size_t)s * 128 * 128,
                                    Wf2_hi + (size_t)s * 2 * 8192,
                                    Wf2_lo + (size_t)s * 2 * 8192, 2);
  }

  const int MB = (N + 63) / 64;  // 782

  // Z = node_fea @ W_top + msg_b (bf16 out)
  k_mm<<<MB, 256, 0, stream>>>(node_fea, WfT_hi, WfT_lo, msg_b, Zb, N, 2);
  // edge messages -> hn
  k_edge<<<E / 128, 512, 0, stream>>>(edge_fea, csr_srcnode, csr_eid, pos2node,
                                      WfB_hi, WfB_lo, Zb, hn);

  // ----- layer 1: A = [node_fea | hn] fp32, K=256 -----
  k_mm3<0><<<MB, 256, 0, stream>>>(node_fea, hn, 2, Wf1_hi, Wf1_lo, norm, YA, C1,
                                   N, 4);
  k_prop2<<<(N + 3) / 4, 256, 0, stream>>>(C1, offs, csr_srcnode, norm, T1, T2, N);
  k_propc<<<(N + 3) / 4, 256, 0, stream>>>(T2, YA, T1, b1, offs, csr_srcnode, norm,
                                           C1 /*H bf16*/, N);

  // ----- layer 2: A = H bf16, K=128 -----
  k_mm3<1><<<MB, 256, 0, stream>>>(C1, nullptr, 0, Wf2_hi, Wf2_lo, norm, YA, C2,
                                   N, 2);
  k_prop2<<<(N + 3) / 4, 256, 0, stream>>>(C2, offs, csr_srcnode, norm, T1, T2, N);
  k_propc<<<(N + 3) / 4, 256, 0, stream>>>(T2, YA, T1, b2, offs, csr_srcnode, norm,
                                           C2 /*H2 bf16*/, N);

  // readout
  k_colsum<<<256, 128, 0, stream>>>(C2, hg, N);
  k_final<<<1, 128, 0, stream>>>(hg, Wp, bp, (float*)d_out, 1.0f / (float)N);
}

// Round 7
// 988.375 us; speedup vs baseline: 7.0353x; 1.4890x over previous
//
#include <hip/hip_runtime.h>
#include <hip/hip_bf16.h>

// ---------------------------------------------------------------------------
// graphNN round 7:
//  - algebraic prop fusion: prop(YB)+prop(prop(YC)) == prop(YB + prop(YC))
//    -> 2 gather passes/layer instead of 3; T1 fp32 buffer eliminated
//  - k_edge: pos2node preloaded to LDS for the walk; nontemporal ef stream
//  - v_cvt_pk_bf16_f32 packing in all staging/epilogue conversions
// ---------------------------------------------------------------------------

typedef __attribute__((ext_vector_type(8))) short short8;
typedef __attribute__((ext_vector_type(4))) float f32x4;
typedef __attribute__((ext_vector_type(4))) unsigned u32x4;
typedef unsigned short ushort_t;

static __device__ __forceinline__ unsigned short f2bf(float x) {
  union { float f; unsigned u; } v{x};
  unsigned r = v.u + 0x7FFF + ((v.u >> 16) & 1);
  return (unsigned short)(r >> 16);
}
static __device__ __forceinline__ float bf2f(unsigned short h) {
  union { unsigned u; float f; } v{(unsigned)h << 16};
  return v.f;
}
static __device__ __forceinline__ float u2f(unsigned u) {
  union { unsigned u; float f; } v{u};
  return v.f;
}
// packed bf16 convert: low16 = bf16(a), high16 = bf16(b)
static __device__ __forceinline__ unsigned cvtpk(float a, float b) {
  unsigned r;
  asm("v_cvt_pk_bf16_f32 %0, %1, %2" : "=v"(r) : "v"(a), "v"(b));
  return r;
}

// ---------- degree histogram ----------
__global__ void k_deg(const int* __restrict__ dst, int* __restrict__ deg, int E) {
  int i = blockIdx.x * blockDim.x + threadIdx.x;
  int stride = gridDim.x * blockDim.x;
  for (; i < E; i += stride) atomicAdd(&deg[dst[i]], 1);
}

// ---------- exclusive scan over deg -> offsets, cursor; also norm ----------
__global__ void k_scan(const int* __restrict__ deg, float* __restrict__ norm,
                       int* __restrict__ offs, int* __restrict__ cursor, int N) {
  __shared__ int part[1024];
  const int t = threadIdx.x;
  const int C = (N + 1023) >> 10;
  const int b = t * C, e = min(b + C, N);
  int s = 0;
  for (int i = b; i < e; ++i) s += deg[i];
  part[t] = s;
  __syncthreads();
  for (int ofs = 1; ofs < 1024; ofs <<= 1) {
    int v = (t >= ofs) ? part[t - ofs] : 0;
    __syncthreads();
    part[t] += v;
    __syncthreads();
  }
  int base = (t == 0) ? 0 : part[t - 1];
  for (int i = b; i < e; ++i) {
    offs[i] = base;
    cursor[i] = base;
    int d = deg[i];
    base += d;
    norm[i] = rsqrtf((float)max(d, 1));
  }
  if (t == 0) offs[N] = part[1023];
}

// ---------- CSR fill ----------
__global__ void k_csr(const int* __restrict__ src, const int* __restrict__ dst,
                      int* __restrict__ cursor, int* __restrict__ csr_srcnode,
                      int* __restrict__ csr_eid, int* __restrict__ pos2node, int E) {
  int i = blockIdx.x * blockDim.x + threadIdx.x;
  int stride = gridDim.x * blockDim.x;
  for (; i < E; i += stride) {
    int d = dst[i];
    int pos = atomicAdd(&cursor[d], 1);
    csr_srcnode[pos] = src[i];
    csr_eid[pos] = i;
    pos2node[pos] = d;
  }
}

// ---------- prep: W [K][128] fp32 -> hi/lo bf16 in MFMA fragment order ------
__global__ void k_prepW(const float* __restrict__ W, ushort_t* __restrict__ Wf_hi,
                        ushort_t* __restrict__ Wf_lo, int KC) {
  int id = blockIdx.x * 256 + threadIdx.x;
  if (id >= KC * 8192) return;
  int j = id & 7;
  int l = (id >> 3) & 63;
  int rest = id >> 9;
  int ks = rest & 1, nt = (rest >> 1) & 7, kc = rest >> 4;
  int k = kc * 64 + ks * 32 + (l >> 4) * 8 + j;
  int col = nt * 16 + (l & 15);
  float w = W[(size_t)k * 128 + col];
  unsigned short hi = f2bf(w);
  unsigned short lo = f2bf(w - bf2f(hi));
  Wf_hi[id] = hi;
  Wf_lo[id] = lo;
}

// stage 16 fp32 -> hi/lo packed LDS slots (helper used by k_mm / k_mm3<0>)
static __device__ __forceinline__ void stage_hilo(const float* base, int sq, int sr,
                                                  ushort_t* Xhi, ushort_t* Xlo) {
#pragma unroll
  for (int i2 = 0; i2 < 2; ++i2) {
    const int o = sq * 2 + i2;
    f32x4 a4 = *(const f32x4*)(base + sq * 16 + i2 * 8);
    f32x4 b4 = *(const f32x4*)(base + sq * 16 + i2 * 8 + 4);
    float x[8] = {a4[0], a4[1], a4[2], a4[3], b4[0], b4[1], b4[2], b4[3]};
    u32x4 vh, vl;
#pragma unroll
    for (int j = 0; j < 4; ++j) {
      unsigned hp = cvtpk(x[2 * j], x[2 * j + 1]);
      float h0 = u2f(hp << 16), h1 = u2f(hp & 0xffff0000u);
      vh[j] = hp;
      vl[j] = cvtpk(x[2 * j] - h0, x[2 * j + 1] - h1);
    }
    const int slot = (sr >> 4) * 128 + o * 16 + (sr & 15);
    *(u32x4*)(Xhi + (size_t)slot * 8) = vh;
    *(u32x4*)(Xlo + (size_t)slot * 8) = vl;
  }
}

// ---------- Z = nf @ W_top + b (fp32 hi/lo in, bf16 out) --------------------
__global__ __launch_bounds__(256) void k_mm(
    const float* __restrict__ A0, const ushort_t* __restrict__ Wf_hi,
    const ushort_t* __restrict__ Wf_lo, const float* __restrict__ bias,
    ushort_t* __restrict__ outZ, int M, int KC) {
  __shared__ __align__(16) char lds[49152];
  ushort_t* Xhi = (ushort_t*)lds;
  ushort_t* Xlo = (ushort_t*)(lds + 8192);
  ushort_t* Whi = (ushort_t*)(lds + 16384);
  ushort_t* Wlo = (ushort_t*)(lds + 32768);

  const int t = threadIdx.x;
  const int m0 = blockIdx.x * 64;
  const int l = t & 63, mt = t >> 6;
  const int sr = t & 63, sq = t >> 6;
  const int row = min(m0 + sr, M - 1);

  f32x4 acc[8];
#pragma unroll
  for (int nt = 0; nt < 8; ++nt) acc[nt] = (f32x4){0.f, 0.f, 0.f, 0.f};

  for (int kc = 0; kc < KC; ++kc) {
    __syncthreads();
    {
      const ulong2* gh = (const ulong2*)(Wf_hi + (size_t)kc * 8192);
      const ulong2* gl = (const ulong2*)(Wf_lo + (size_t)kc * 8192);
#pragma unroll
      for (int i = 0; i < 4; ++i) {
        ((ulong2*)Whi)[i * 256 + t] = gh[i * 256 + t];
        ((ulong2*)Wlo)[i * 256 + t] = gl[i * 256 + t];
      }
    }
    stage_hilo(A0 + (size_t)row * 128 + kc * 64, sq, sr, Xhi, Xlo);
    __syncthreads();
    const short8* Xh8 = (const short8*)Xhi;
    const short8* Xl8 = (const short8*)Xlo;
    const short8* Wh8 = (const short8*)Whi;
    const short8* Wl8 = (const short8*)Wlo;
#pragma unroll
    for (int ks = 0; ks < 2; ++ks) {
      short8 ah = Xh8[mt * 128 + ks * 64 + l];
      short8 al = Xl8[mt * 128 + ks * 64 + l];
#pragma unroll
      for (int nt = 0; nt < 8; ++nt) {
        short8 bh = Wh8[(nt * 2 + ks) * 64 + l];
        short8 bl = Wl8[(nt * 2 + ks) * 64 + l];
        acc[nt] = __builtin_amdgcn_mfma_f32_16x16x32_bf16(ah, bh, acc[nt], 0, 0, 0);
        acc[nt] = __builtin_amdgcn_mfma_f32_16x16x32_bf16(al, bh, acc[nt], 0, 0, 0);
        acc[nt] = __builtin_amdgcn_mfma_f32_16x16x32_bf16(ah, bl, acc[nt], 0, 0, 0);
      }
    }
  }
  const int l15 = l & 15, lh = l >> 4;
#pragma unroll
  for (int nt = 0; nt < 8; ++nt) {
    const int col = nt * 16 + l15;
#pragma unroll
    for (int rg = 0; rg < 4; ++rg) {
      const int r = m0 + mt * 16 + lh * 4 + rg;
      if (r < M) outZ[(size_t)r * 128 + col] = f2bf(acc[nt][rg] + bias[col]);
    }
  }
}

// ---------- fused 3-slice GEMM: YA fp32, YBt bf16, YCt bf16 (rowscaled) -----
template <int BF16A>
__global__ __launch_bounds__(256) void k_mm3(
    const void* __restrict__ A0v, const float* __restrict__ A1, int split64,
    const ushort_t* __restrict__ Wf_hi, const ushort_t* __restrict__ Wf_lo,
    const float* __restrict__ rowscale, float* __restrict__ outA,
    ushort_t* __restrict__ outYB, ushort_t* __restrict__ outYC, int M, int KC) {
  __shared__ __align__(16) char lds[49152];
  ushort_t* Xhi = (ushort_t*)lds;
  ushort_t* Xlo = (ushort_t*)(lds + 8192);
  ushort_t* Whi = (ushort_t*)(lds + 16384);
  ushort_t* Wlo = (ushort_t*)(lds + 32768);

  const int t = threadIdx.x;
  const int m0 = blockIdx.x * 64;
  const int l = t & 63, mt = t >> 6;
  const int sr = t & 63, sq = t >> 6;
  const int row = min(m0 + sr, M - 1);

  f32x4 acc[3][8];
#pragma unroll
  for (int s = 0; s < 3; ++s)
#pragma unroll
    for (int nt = 0; nt < 8; ++nt) acc[s][nt] = (f32x4){0.f, 0.f, 0.f, 0.f};

  for (int kc = 0; kc < KC; ++kc) {
    __syncthreads();
    if constexpr (BF16A) {
      const ushort_t* base = (const ushort_t*)A0v + (size_t)row * 128 + kc * 64;
#pragma unroll
      for (int i2 = 0; i2 < 2; ++i2) {
        const int o = sq * 2 + i2;
        short8 v = *(const short8*)(base + sq * 16 + i2 * 8);
        const int slot = (sr >> 4) * 128 + o * 16 + (sr & 15);
        *(short8*)(Xhi + (size_t)slot * 8) = v;
      }
    } else {
      const float* A0 = (const float*)A0v;
      const float* base = (kc < split64) ? (A0 + (size_t)row * 128 + kc * 64)
                                         : (A1 + (size_t)row * 128 + (kc - split64) * 64);
      stage_hilo(base, sq, sr, Xhi, Xlo);
    }
#pragma unroll
    for (int s = 0; s < 3; ++s) {
      if (s) __syncthreads();
      {
        const ulong2* gh = (const ulong2*)(Wf_hi + ((size_t)s * KC + kc) * 8192);
        const ulong2* gl = (const ulong2*)(Wf_lo + ((size_t)s * KC + kc) * 8192);
#pragma unroll
        for (int i = 0; i < 4; ++i) {
          ((ulong2*)Whi)[i * 256 + t] = gh[i * 256 + t];
          ((ulong2*)Wlo)[i * 256 + t] = gl[i * 256 + t];
        }
      }
      __syncthreads();
      const short8* Xh8 = (const short8*)Xhi;
      const short8* Xl8 = (const short8*)Xlo;
      const short8* Wh8 = (const short8*)Whi;
      const short8* Wl8 = (const short8*)Wlo;
#pragma unroll
      for (int ks = 0; ks < 2; ++ks) {
        short8 ah = Xh8[mt * 128 + ks * 64 + l];
        short8 al;
        if constexpr (!BF16A) al = Xl8[mt * 128 + ks * 64 + l];
#pragma unroll
        for (int nt = 0; nt < 8; ++nt) {
          short8 bh = Wh8[(nt * 2 + ks) * 64 + l];
          short8 bl = Wl8[(nt * 2 + ks) * 64 + l];
          acc[s][nt] = __builtin_amdgcn_mfma_f32_16x16x32_bf16(ah, bh, acc[s][nt], 0, 0, 0);
          if constexpr (!BF16A)
            acc[s][nt] = __builtin_amdgcn_mfma_f32_16x16x32_bf16(al, bh, acc[s][nt], 0, 0, 0);
          acc[s][nt] = __builtin_amdgcn_mfma_f32_16x16x32_bf16(ah, bl, acc[s][nt], 0, 0, 0);
        }
      }
    }
  }
  const int l15 = l & 15, lh = l >> 4;
#pragma unroll
  for (int rg = 0; rg < 4; ++rg) {
    const int r = m0 + mt * 16 + lh * 4 + rg;
    if (r < M) {
      const float rs = rowscale[r];
#pragma unroll
      for (int nt = 0; nt < 8; ++nt) {
        const int col = nt * 16 + l15;
        outA[(size_t)r * 128 + col] = acc[0][nt][rg];
        outYB[(size_t)r * 128 + col] = f2bf(acc[1][nt][rg] * rs);
        outYC[(size_t)r * 128 + col] = f2bf(acc[2][nt][rg] * rs);
      }
    }
  }
}

// ---------- edge GEMM (K=64, bf16 ef) + bf16 Z + parallel walk --------------
// 128 edges/block, 512 threads. LDS 48KB -> 3 blocks/CU.
__global__ __launch_bounds__(512, 6) void k_edge(
    const float* __restrict__ ef, const int* __restrict__ csr_srcnode,
    const int* __restrict__ csr_eid, const int* __restrict__ pos2node,
    const ushort_t* __restrict__ WfB_hi, const ushort_t* __restrict__ WfB_lo,
    const ushort_t* __restrict__ Zb, float* __restrict__ h_neigh) {
  __shared__ __align__(16) char lds[49152];
  ushort_t* Xh = (ushort_t*)lds;             // [0,16K)
  ushort_t* Whi = (ushort_t*)(lds + 16384);  // [16K,32K)
  ushort_t* Wlo = (ushort_t*)(lds + 32768);  // [32K,48K)
  ushort_t* Cs = (ushort_t*)lds;             // epilogue overlay [128][128] bf16 = 32KB
  int* sN = (int*)(lds + 32768);             // epilogue overlay over Wlo (512B)

  const int t = threadIdx.x;
  const int b0 = blockIdx.x * 128;
  const int l = t & 63, mt = t >> 6;
  const int col = t & 127, q = t >> 7;
  const int rbase = b0 + q * 32;

  // ---- Z prefetch (bf16, packed 2/reg), consumed only in the walk ----
  unsigned zp[16];
#pragma unroll
  for (int i = 0; i < 16; ++i) {
    unsigned a = Zb[(size_t)csr_srcnode[rbase + 2 * i] * 128 + col];
    unsigned b = Zb[(size_t)csr_srcnode[rbase + 2 * i + 1] * 128 + col];
    zp[i] = a | (b << 16);
  }
  // ---- stage W hi/lo (2 x 16KB linear) ----
  {
    const ulong2* gh = (const ulong2*)WfB_hi;
    const ulong2* gl = (const ulong2*)WfB_lo;
#pragma unroll
    for (int i = 0; i < 2; ++i) {
      ((ulong2*)Whi)[i * 512 + t] = gh[i * 512 + t];
      ((ulong2*)Wlo)[i * 512 + t] = gl[i * 512 + t];
    }
  }
  // ---- stage ef rows, bf16 hi only, nontemporal stream, cvt_pk ----
  {
    const int row = t >> 2, part = t & 3;
    const int eid = csr_eid[b0 + row];
    const float* rowp = ef + (size_t)eid * 64 + part * 16;
#pragma unroll
    for (int i2 = 0; i2 < 2; ++i2) {
      const int o = part * 2 + i2;
      f32x4 a4 = __builtin_nontemporal_load((const f32x4*)(rowp + i2 * 8));
      f32x4 b4 = __builtin_nontemporal_load((const f32x4*)(rowp + i2 * 8 + 4));
      u32x4 vh;
      vh[0] = cvtpk(a4[0], a4[1]);
      vh[1] = cvtpk(a4[2], a4[3]);
      vh[2] = cvtpk(b4[0], b4[1]);
      vh[3] = cvtpk(b4[2], b4[3]);
      const int slot = (row >> 4) * 128 + o * 16 + (row & 15);
      *(u32x4*)(Xh + (size_t)slot * 8) = vh;
    }
  }
  __syncthreads();

  f32x4 acc[8];
#pragma unroll
  for (int nt = 0; nt < 8; ++nt) acc[nt] = (f32x4){0.f, 0.f, 0.f, 0.f};
  {
    const short8* Xh8 = (const short8*)Xh;
    const short8* Wh8 = (const short8*)Whi;
    const short8* Wl8 = (const short8*)Wlo;
#pragma unroll
    for (int ks = 0; ks < 2; ++ks) {
      short8 ah = Xh8[mt * 128 + ks * 64 + l];
#pragma unroll
      for (int nt = 0; nt < 8; ++nt) {
        short8 bh = Wh8[(nt * 2 + ks) * 64 + l];
        short8 bl = Wl8[(nt * 2 + ks) * 64 + l];
        acc[nt] = __builtin_amdgcn_mfma_f32_16x16x32_bf16(ah, bh, acc[nt], 0, 0, 0);
        acc[nt] = __builtin_amdgcn_mfma_f32_16x16x32_bf16(ah, bl, acc[nt], 0, 0, 0);
      }
    }
  }
  __syncthreads();
  // ---- preload segment node ids (over dead Wlo region) + C tile to LDS ----
  if (t < 128) sN[t] = pos2node[b0 + t];
  const int l15 = l & 15, lh = l >> 4;
#pragma unroll
  for (int nt = 0; nt < 8; ++nt) {
#pragma unroll
    for (int rg = 0; rg < 4; ++rg) {
      const int row = mt * 16 + lh * 4 + rg;
      const int c = nt * 16 + l15;
      Cs[row * 128 + (c ^ (((row >> 2) & 3) << 4))] = f2bf(acc[nt][rg]);
    }
  }
  __syncthreads();
  // ---- 4-way parallel segment walk ----
  {
    int node = sN[q * 32];
    float ssum = 0.f;
#pragma unroll
    for (int r = 0; r < 32; ++r) {
      const int rr = q * 32 + r;
      float cz = bf2f(Cs[rr * 128 + (col ^ (((rr >> 2) & 3) << 4))]);
      float zf = u2f((r & 1) ? (zp[r >> 1] & 0xffff0000u) : (zp[r >> 1] << 16));
      float v = fmaxf(cz + zf, 0.f);
      if (r == 0) {
        ssum = v;
      } else {
        int n2 = sN[rr];
        if (n2 == node) {
          ssum += v;
        } else {
          unsafeAtomicAdd(&h_neigh[(size_t)node * 128 + col], ssum);
          node = n2;
          ssum = v;
        }
      }
    }
    unsafeAtomicAdd(&h_neigh[(size_t)node * 128 + col], ssum);
  }
}

// ---------- propA: Qt[v] = YBt[v] + n_v^2 * sum YCt[src]  (all bf16) --------
__global__ __launch_bounds__(256) void k_propA(
    const ushort_t* __restrict__ YCt, const ushort_t* __restrict__ YBt,
    const int* __restrict__ offs, const int* __restrict__ csr_src,
    const float* __restrict__ norm, ushort_t* __restrict__ Qt, int N) {
  const int v = blockIdx.x * 4 + (threadIdx.x >> 6);
  const int lane = threadIdx.x & 63;
  if (v >= N) return;
  const int b = offs[v], e = offs[v + 1];
  const unsigned* yc = (const unsigned*)YCt;
  float ax = 0.f, ay = 0.f;
#pragma unroll 4
  for (int i = b; i < e; ++i) {
    unsigned x = yc[(size_t)csr_src[i] * 64 + lane];
    ax += u2f(x << 16);
    ay += u2f(x & 0xffff0000u);
  }
  float n = norm[v];
  float n2 = n * n;
  unsigned yb = ((const unsigned*)YBt)[(size_t)v * 64 + lane];
  float qx = u2f(yb << 16) + n2 * ax;
  float qy = u2f(yb & 0xffff0000u) + n2 * ay;
  ((unsigned*)Qt)[(size_t)v * 64 + lane] = cvtpk(qx, qy);
}

// ---------- propB: H[v] = relu(YA[v] + n_v * sum Qt[src] + b)  (bf16 out) ---
__global__ __launch_bounds__(256) void k_propB(
    const ushort_t* __restrict__ Qt, const float* __restrict__ YA,
    const float* __restrict__ bias, const int* __restrict__ offs,
    const int* __restrict__ csr_src, const float* __restrict__ norm,
    ushort_t* __restrict__ H, int N) {
  const int v = blockIdx.x * 4 + (threadIdx.x >> 6);
  const int lane = threadIdx.x & 63;
  if (v >= N) return;
  const int b = offs[v], e = offs[v + 1];
  const unsigned* qp = (const unsigned*)Qt;
  float ax = 0.f, ay = 0.f;
#pragma unroll 4
  for (int i = b; i < e; ++i) {
    unsigned x = qp[(size_t)csr_src[i] * 64 + lane];
    ax += u2f(x << 16);
    ay += u2f(x & 0xffff0000u);
  }
  float n = norm[v];
  float2 ya = ((const float2*)YA)[(size_t)v * 64 + lane];
  float2 bb = ((const float2*)bias)[lane];
  float hx = fmaxf(ya.x + n * ax + bb.x, 0.f);
  float hy = fmaxf(ya.y + n * ay + bb.y, 0.f);
  ((unsigned*)H)[(size_t)v * 64 + lane] = cvtpk(hx, hy);
}

// ---------- column sums of bf16 h -> hg[128] ----------
__global__ void k_colsum(const ushort_t* __restrict__ h, float* __restrict__ hg, int N) {
  const int t = threadIdx.x;  // 128
  const int per = (N + gridDim.x - 1) / gridDim.x;
  const int n0 = blockIdx.x * per, n1 = min(n0 + per, N);
  float s = 0.f;
  for (int n = n0; n < n1; ++n) s += bf2f(h[(size_t)n * 128 + t]);
  unsafeAtomicAdd(&hg[t], s);
}

// ---------- final ----------
__global__ void k_final(const float* __restrict__ hg, const float* __restrict__ Wp,
                        const float* __restrict__ bp, float* __restrict__ out,
                        float invN) {
  __shared__ float red[128];
  const int t = threadIdx.x;
  red[t] = hg[t] * invN * Wp[t];
  __syncthreads();
  for (int s = 64; s > 0; s >>= 1) {
    if (t < s) red[t] += red[t + s];
    __syncthreads();
  }
  if (t == 0) out[0] = red[0] + bp[0];
}

extern "C" void kernel_launch(void* const* d_in, const int* in_sizes, int n_in,
                              void* d_out, int out_size, void* d_ws, size_t ws_size,
                              hipStream_t stream) {
  const float* node_fea = (const float*)d_in[0];
  const float* edge_fea = (const float*)d_in[1];
  const int* src = (const int*)d_in[2];
  const int* dst = (const int*)d_in[3];
  const float* msg_W = (const float*)d_in[4];
  const float* msg_b = (const float*)d_in[5];
  const float* W1 = (const float*)d_in[6];
  const float* b1 = (const float*)d_in[7];
  const float* W2 = (const float*)d_in[8];
  const float* b2 = (const float*)d_in[9];
  const float* Wp = (const float*)d_in[10];
  const float* bp = (const float*)d_in[11];

  const int N = in_sizes[0] / 128;  // 50000
  const int E = in_sizes[2];        // 1600000

  char* p = (char*)d_ws;
  auto alloc = [&](size_t bytes) {
    char* r = p;
    p += (bytes + 255) & ~(size_t)255;
    return r;
  };
  int* deg = (int*)alloc((size_t)N * 4);
  float* norm = (float*)alloc((size_t)N * 4);
  int* offs = (int*)alloc((size_t)(N + 1) * 4);
  int* cursor = (int*)alloc((size_t)N * 4);
  int* csr_srcnode = (int*)alloc((size_t)E * 4);
  int* csr_eid = (int*)alloc((size_t)E * 4);
  int* pos2node = (int*)alloc((size_t)E * 4);
  ushort_t* WfT_hi = (ushort_t*)alloc(2 * 8192 * 2);
  ushort_t* WfT_lo = (ushort_t*)alloc(2 * 8192 * 2);
  ushort_t* WfB_hi = (ushort_t*)alloc(1 * 8192 * 2);
  ushort_t* WfB_lo = (ushort_t*)alloc(1 * 8192 * 2);
  ushort_t* Wf1_hi = (ushort_t*)alloc(3 * 4 * 8192 * 2);
  ushort_t* Wf1_lo = (ushort_t*)alloc(3 * 4 * 8192 * 2);
  ushort_t* Wf2_hi = (ushort_t*)alloc(3 * 2 * 8192 * 2);
  ushort_t* Wf2_lo = (ushort_t*)alloc(3 * 2 * 8192 * 2);
  ushort_t* Zb = (ushort_t*)alloc((size_t)N * 128 * 2);   // bf16 Z
  float* YA = (float*)alloc((size_t)N * 128 * 4);         // fp32 (both layers)
  float* hn = (float*)alloc((size_t)N * 128 * 4);         // fp32 (atomic target)
  ushort_t* YBt = (ushort_t*)alloc((size_t)N * 128 * 2);  // bf16 n*YB
  ushort_t* YCt = (ushort_t*)alloc((size_t)N * 128 * 2);  // bf16 n*YC
  ushort_t* Qt = (ushort_t*)alloc((size_t)N * 128 * 2);   // bf16 n*(YB+prop(YC))
  ushort_t* H1 = (ushort_t*)alloc((size_t)N * 128 * 2);   // bf16 layer-1 out
  ushort_t* H2 = (ushort_t*)alloc((size_t)N * 128 * 2);   // bf16 layer-2 out
  float* hg = (float*)alloc(128 * 4);

  hipMemsetAsync(deg, 0, (size_t)N * 4, stream);
  hipMemsetAsync(hn, 0, (size_t)N * 128 * 4, stream);
  hipMemsetAsync(hg, 0, 128 * 4, stream);

  // graph structure
  k_deg<<<2048, 256, 0, stream>>>(dst, deg, E);
  k_scan<<<1, 1024, 0, stream>>>(deg, norm, offs, cursor, N);
  k_csr<<<2048, 256, 0, stream>>>(src, dst, cursor, csr_srcnode, csr_eid, pos2node, E);

  // weight prep
  k_prepW<<<64, 256, 0, stream>>>(msg_W, WfT_hi, WfT_lo, 2);
  k_prepW<<<32, 256, 0, stream>>>(msg_W + 128 * 128, WfB_hi, WfB_lo, 1);
  for (int s = 0; s < 3; ++s) {
    k_prepW<<<128, 256, 0, stream>>>(W1 + (size_t)s * 256 * 128,
                                     Wf1_hi + (size_t)s * 4 * 8192,
                                     Wf1_lo + (size_t)s * 4 * 8192, 4);
    k_prepW<<<64, 256, 0, stream>>>(W2 + (size_t)s * 128 * 128,
                                    Wf2_hi + (size_t)s * 2 * 8192,
                                    Wf2_lo + (size_t)s * 2 * 8192, 2);
  }

  const int MB = (N + 63) / 64;  // 782
  const int PB = (N + 3) / 4;

  // Z = node_fea @ W_top + msg_b (bf16 out)
  k_mm<<<MB, 256, 0, stream>>>(node_fea, WfT_hi, WfT_lo, msg_b, Zb, N, 2);
  // edge messages -> hn
  k_edge<<<E / 128, 512, 0, stream>>>(edge_fea, csr_srcnode, csr_eid, pos2node,
                                      WfB_hi, WfB_lo, Zb, hn);

  // ----- layer 1: A = [node_fea | hn] fp32, K=256 -----
  k_mm3<0><<<MB, 256, 0, stream>>>(node_fea, hn, 2, Wf1_hi, Wf1_lo, norm, YA,
                                   YBt, YCt, N, 4);
  k_propA<<<PB, 256, 0, stream>>>(YCt, YBt, offs, csr_srcnode, norm, Qt, N);
  k_propB<<<PB, 256, 0, stream>>>(Qt, YA, b1, offs, csr_srcnode, norm, H1, N);

  // ----- layer 2: A = H1 bf16, K=128 -----
  k_mm3<1><<<MB, 256, 0, stream>>>(H1, nullptr, 0, Wf2_hi, Wf2_lo, norm, YA,
                                   YBt, YCt, N, 2);
  k_propA<<<PB, 256, 0, stream>>>(YCt, YBt, offs, csr_srcnode, norm, Qt, N);
  k_propB<<<PB, 256, 0, stream>>>(Qt, YA, b2, offs, csr_srcnode, norm, H2, N);

  // readout
  k_colsum<<<256, 128, 0, stream>>>(H2, hg, N);
  k_final<<<1, 128, 0, stream>>>(hg, Wp, bp, (float*)d_out, 1.0f / (float)N);
}